// Round 7
// baseline (575.804 us; speedup 1.0000x reference)
//
#include <hip/hip_runtime.h>
#include <stdint.h>

// Problem constants
#define N_ENTS  100000
#define M_PAD   100096          // 782 * 128
#define N_RELS  16
#define DIM     128
#define NB      4
#define KTOT    640             // 128 (self) + 4*128 (bases)
#define NEDGE   640000
#define BATCH   1024
#define NNEG    64
#define BN_EPS  1e-5f
#define NBLK    782             // M_PAD/128

// converted-parameter buffer layout (ushort offsets)
#define P_REL    0        // [16][128]
#define P_BASES  2048     // [2][4][128][128]
#define P_COEFF  133120   // [2][16][4]
#define P_WSL    133248   // [2][128][128]
#define P_BSL    166016   // [2][128]
#define P_GAMMA  166272   // [2][128]
#define P_BETA   166528   // [2][128]
#define P_TOTAL  166784

typedef unsigned int uint;
typedef short short8 __attribute__((ext_vector_type(8)));
typedef float f4 __attribute__((ext_vector_type(4)));

// bf16 helpers
__device__ __forceinline__ float bf2f(unsigned short u) {
    return __uint_as_float(((unsigned int)u) << 16);
}
__device__ __forceinline__ float bflo(unsigned int u) { return __uint_as_float(u << 16); }
__device__ __forceinline__ float bfhi(unsigned int u) { return __uint_as_float(u & 0xffff0000u); }
__device__ __forceinline__ unsigned short f2bf(float f) {
    unsigned int x = __float_as_uint(f);
    x += 0x7fffu + ((x >> 16) & 1u);
    return (unsigned short)(x >> 16);
}
__device__ __forceinline__ unsigned int pack2(float a, float b) {
    return (unsigned int)f2bf(a) | ((unsigned int)f2bf(b) << 16);
}

// ---------------- dtype detection (fp32 vs bf16 storage) ----------------
__device__ __forceinline__ int bf16_like(unsigned int h) {
    unsigned int m = h & 0x7FFFu;
    return (m == 0u) || (m >= 0x2D00u && m < 0x4400u);
}
__global__ __launch_bounds__(256) void k_detect(const unsigned int* __restrict__ ent,
                                                int* __restrict__ flag) {
    __shared__ int cnt[256];
    unsigned int u = ent[threadIdx.x];
    cnt[threadIdx.x] = bf16_like(u & 0xFFFFu) & bf16_like(u >> 16);
    __syncthreads();
    for (int s = 128; s > 0; s >>= 1) {
        if (threadIdx.x < s) cnt[threadIdx.x] += cnt[threadIdx.x + s];
        __syncthreads();
    }
    if (threadIdx.x == 0) flag[0] = (cnt[0] >= 140) ? 1 : 0;
}

// ---------------- converts ----------------
__device__ __forceinline__ unsigned short cvt1(const void* src, int i, int isbf) {
    return isbf ? ((const unsigned short*)src)[i] : f2bf(((const float*)src)[i]);
}
// all small params -> par[], one dispatch
__global__ __launch_bounds__(256) void k_conv_params(
    const void* __restrict__ rtab, const void* __restrict__ bases,
    const void* __restrict__ coeffs, const void* __restrict__ wsl,
    const void* __restrict__ bsl, const void* __restrict__ gamma,
    const void* __restrict__ beta,
    unsigned short* __restrict__ par, const int* __restrict__ flag)
{
    const int i = blockIdx.x * 256 + threadIdx.x;
    if (i >= P_TOTAL) return;
    const int isbf = flag[0];
    unsigned short v;
    if      (i < P_BASES)  v = cvt1(rtab,   i - P_REL,    isbf);
    else if (i < P_COEFF)  v = cvt1(bases,  i - P_BASES,  isbf);
    else if (i < P_WSL)    v = cvt1(coeffs, i - P_COEFF,  isbf);
    else if (i < P_BSL)    v = cvt1(wsl,    i - P_WSL,    isbf);
    else if (i < P_GAMMA)  v = cvt1(bsl,    i - P_BSL,    isbf);
    else if (i < P_BETA)   v = cvt1(gamma,  i - P_GAMMA,  isbf);
    else                   v = cvt1(beta,   i - P_BETA,   isbf);
    par[i] = v;
}
// entity -> xy rows (stride KTOT), cols [0,128), 4 elems/thread
__global__ __launch_bounds__(256) void k_conv_x(const void* __restrict__ src,
                                                unsigned short* __restrict__ xy,
                                                const int* __restrict__ flag) {
    const int i4 = blockIdx.x * 256 + threadIdx.x;   // grid exact: N_ENTS*DIM/4/256
    const int i = i4 * 4;
    const int n = i >> 7, d = i & 127;
    uint2 w;
    if (flag[0]) {
        w = *(const uint2*)((const unsigned short*)src + i);
    } else {
        const float4 f = *(const float4*)((const float*)src + i);
        w.x = pack2(f.x, f.y);
        w.y = pack2(f.z, f.w);
    }
    *(uint2*)(xy + (size_t)n * KTOT + d) = w;
}

// ---------------- CSR build (counting sort by dst) ----------------
__global__ __launch_bounds__(256) void k_count(const int* __restrict__ dst, int* __restrict__ cnt) {
    int e = blockIdx.x * 256 + threadIdx.x;
    if (e < NEDGE) atomicAdd(&cnt[dst[e]], 1);
}
__global__ __launch_bounds__(256) void k_bsum(const int* __restrict__ cnt, int* __restrict__ bsum) {
    __shared__ int l[256];
    int i = blockIdx.x * 256 + threadIdx.x;
    l[threadIdx.x] = (i < N_ENTS) ? cnt[i] : 0;
    __syncthreads();
    for (int s = 128; s > 0; s >>= 1) {
        if (threadIdx.x < s) l[threadIdx.x] += l[threadIdx.x + s];
        __syncthreads();
    }
    if (threadIdx.x == 0) bsum[blockIdx.x] = l[0];
}
__global__ __launch_bounds__(512) void k_scan1(int* __restrict__ bsum) {  // 391 partials
    __shared__ int tmp[512];
    const int t = threadIdx.x;
    const int v = (t < 391) ? bsum[t] : 0;
    tmp[t] = v;
    __syncthreads();
    for (int off = 1; off < 512; off <<= 1) {
        int u = (t >= off) ? tmp[t - off] : 0;
        __syncthreads();
        tmp[t] += u;
        __syncthreads();
    }
    if (t < 391) bsum[t] = tmp[t] - v;   // exclusive
}
__global__ __launch_bounds__(256) void k_starts(const int* __restrict__ cnt,
                                                const int* __restrict__ boff,
                                                int* __restrict__ starts) {
    __shared__ int tmp[256];
    const int t = threadIdx.x;
    const int i = blockIdx.x * 256 + t;
    const int v = (i < N_ENTS) ? cnt[i] : 0;
    tmp[t] = v;
    __syncthreads();
    for (int off = 1; off < 256; off <<= 1) {
        int u = (t >= off) ? tmp[t - off] : 0;
        __syncthreads();
        tmp[t] += u;
        __syncthreads();
    }
    if (i < N_ENTS) starts[i] = tmp[t] - v + boff[blockIdx.x];
}
__global__ __launch_bounds__(256) void k_fill(const int* __restrict__ src, const int* __restrict__ dst,
                                              const int* __restrict__ et, const int* __restrict__ starts,
                                              int* __restrict__ cur, uint* __restrict__ ebuf) {
    int e = blockIdx.x * 256 + threadIdx.x;
    if (e >= NEDGE) return;
    const int d = dst[e];
    const int p = atomicAdd(&cur[d], 1);
    ebuf[starts[d] + p] = (uint)src[e] | ((uint)et[e] << 20);
}

// ---------------- edge aggregation (gather, no atomics, 4-stream ILP) ----------------
__global__ __launch_bounds__(256) void k_agg(
    const uint* __restrict__ ebuf, const int* __restrict__ starts, const int* __restrict__ cnt,
    const unsigned short* __restrict__ coeffs /* [16][4] layer slice */,
    unsigned short* __restrict__ xy)
{
    __shared__ uint2 scf[16];
    if (threadIdx.x < 16) scf[threadIdx.x] = *(const uint2*)(coeffs + threadIdx.x * 4);
    __syncthreads();
    const int wave = threadIdx.x >> 6, lane = threadIdx.x & 63;
    const int n = blockIdx.x * 4 + wave;   // grid exact: N_ENTS/4
    const int c0 = starts[n], cn = cnt[n];
    const int q = (cn + 3) >> 2;
    float lo[4][NB] = {}, hi[4][NB] = {};
    const uint* __restrict__ x32 = (const uint*)xy;
    for (int i = 0; i < q; ++i) {
        uint rec[4];
        int valid[4];
#pragma unroll
        for (int s = 0; s < 4; ++s) {
            const int p = s * q + i;
            valid[s] = p < cn;
            rec[s] = ebuf[c0 + (valid[s] ? p : 0)];
        }
        uint xw[4];
#pragma unroll
        for (int s = 0; s < 4; ++s)
            xw[s] = x32[(size_t)(rec[s] & 0xFFFFFu) * (KTOT / 2) + lane];
#pragma unroll
        for (int s = 0; s < 4; ++s) {
            uint2 cc = scf[rec[s] >> 20];
            if (!valid[s]) { cc.x = 0; cc.y = 0; }
            const float cb[NB] = {bflo(cc.x), bfhi(cc.x), bflo(cc.y), bfhi(cc.y)};
            const float xl = bflo(xw[s]), xh = bfhi(xw[s]);
#pragma unroll
            for (int b = 0; b < NB; ++b) {
                lo[s][b] = fmaf(cb[b], xl, lo[s][b]);
                hi[s][b] = fmaf(cb[b], xh, hi[s][b]);
            }
        }
    }
    uint* xyw = (uint*)xy;
#pragma unroll
    for (int b = 0; b < NB; ++b) {
        const float l = (lo[0][b] + lo[1][b]) + (lo[2][b] + lo[3][b]);
        const float h = (hi[0][b] + hi[1][b]) + (hi[2][b] + hi[3][b]);
        xyw[(size_t)n * (KTOT / 2) + 64 + b * 64 + lane] = pack2(l, h);
    }
}

// ---------------- build Wt for BOTH layers: Wt[l][n=128][k=640] ----------------
__global__ __launch_bounds__(256) void k_transw2(const unsigned short* __restrict__ par,
                                                 unsigned short* __restrict__ Wt) {
    const int i = blockIdx.x * 256 + threadIdx.x;   // grid exact: 2*640*128/256 = 640
    const int l = i / (KTOT * DIM);                  // 81920 elements per layer
    const int rem = i - l * (KTOT * DIM);
    const int k = rem >> 7, n = rem & 127;
    const unsigned short v = (k < DIM)
        ? par[P_WSL + l * DIM * DIM + k * DIM + n]
        : par[P_BASES + l * NB * DIM * DIM + (k - DIM) * DIM + n];
    Wt[(size_t)l * DIM * KTOT + n * KTOT + k] = v;
}

// ---------------- barrier-free MFMA GEMM, explicit register double-buffer ----------------
// C[M_PAD x 128] = xy[M_PAD x 640] @ Wt^T ; 4 waves = 2x2 of 64x64, frags global->reg,
// kc-loop unrolled x2 with two independent register sets so 16 loads stay in flight
// during MFMA (fixes the 1-batch-in-flight latency serialization seen in round 6).
__global__ __launch_bounds__(256, 2) void k_gemm(
    const unsigned short* __restrict__ xy, const unsigned short* __restrict__ Wt,
    const unsigned short* __restrict__ bsl, const int* __restrict__ cnt,
    float* __restrict__ out, float* __restrict__ pstats)
{
    const int tid = threadIdx.x;
    const int wave = tid >> 6, lane = tid & 63;
    const int quad = lane >> 4, l16 = lane & 15;
    const int m0 = blockIdx.x * 128;
    const int rbase = (wave >> 1) * 64;   // wave row offset in tile
    const int col0 = (wave & 1) * 64;     // wave col offset

    // fragment load bases (A-operand: lane holds A[m=l16][k=quad*8+j])
    const unsigned short* pa = xy + (size_t)(m0 + rbase + l16) * KTOT + quad * 8;
    const unsigned short* pb = Wt + (size_t)(col0 + l16) * KTOT + quad * 8;

    f4 acc[4][4];
#pragma unroll
    for (int i = 0; i < 4; ++i)
#pragma unroll
        for (int j = 0; j < 4; ++j)
#pragma unroll
            for (int r = 0; r < 4; ++r) acc[i][j][r] = 0.f;

    short8 A0[4][2], B0[4][2], A1[4][2], B1[4][2];

    auto LD = [&](short8 (&Av)[4][2], short8 (&Bv)[4][2], int kc) {
#pragma unroll
        for (int i = 0; i < 4; ++i)
#pragma unroll
            for (int ks = 0; ks < 2; ++ks) {
                Av[i][ks] = *(const short8*)(pa + (size_t)i * 16 * KTOT + kc * 64 + ks * 32);
                Bv[i][ks] = *(const short8*)(pb + (size_t)i * 16 * KTOT + kc * 64 + ks * 32);
            }
    };
    auto MM = [&](short8 (&Av)[4][2], short8 (&Bv)[4][2]) {
#pragma unroll
        for (int ks = 0; ks < 2; ++ks)
#pragma unroll
            for (int i = 0; i < 4; ++i)
#pragma unroll
                for (int j = 0; j < 4; ++j)
                    acc[i][j] = __builtin_amdgcn_mfma_f32_16x16x32_bf16(Av[i][ks], Bv[j][ks], acc[i][j], 0, 0, 0);
    };

    LD(A0, B0, 0);
#pragma unroll
    for (int kc = 0; kc < KTOT / 64; kc += 2) {
        LD(A1, B1, kc + 1);              // prefetch next chunk before consuming current
        MM(A0, B0);
        if (kc + 2 < KTOT / 64) LD(A0, B0, kc + 2);
        MM(A1, B1);
    }

    // epilogue: o = (acc + bias)/deg ; store fp32 ; block-local BN stats (no global atomics)
    float s_sum[4] = {0, 0, 0, 0}, s_ssq[4] = {0, 0, 0, 0};
#pragma unroll
    for (int i = 0; i < 4; ++i) {
#pragma unroll
        for (int r = 0; r < 4; ++r) {
            const int row = m0 + rbase + i * 16 + quad * 4 + r;    // C/D: row = quad*4+reg
            const int rc = row < N_ENTS ? row : N_ENTS - 1;
            const float rdeg = 1.0f / fmaxf((float)cnt[rc], 1.0f);
            const bool valid = row < N_ENTS;
#pragma unroll
            for (int j = 0; j < 4; ++j) {
                const int f = col0 + j * 16 + l16;                 // C/D: col = lane&15
                const float o = (acc[i][j][r] + bf2f(bsl[f])) * rdeg;
                if (valid) {
                    out[(size_t)row * DIM + f] = o;
                    s_sum[j] += o;
                    s_ssq[j] += o * o;
                }
            }
        }
    }
    __shared__ float ssum[4][64], sssq[4][64];
#pragma unroll
    for (int j = 0; j < 4; ++j) {
        float s = s_sum[j], q = s_ssq[j];
        s += __shfl_xor(s, 16, 64); s += __shfl_xor(s, 32, 64);
        q += __shfl_xor(q, 16, 64); q += __shfl_xor(q, 32, 64);
        if (quad == 0) {
            ssum[wave][j * 16 + l16] = s;
            sssq[wave][j * 16 + l16] = q;
        }
    }
    __syncthreads();
    // pstats[blk][0..127]=sum per f, [128..255]=ssq per f
    {
        const int f = tid & 127;
        const int g = f >> 6;         // col group: waves {g, g+2}
        const int fl = f & 63;
        const float v = (tid < 128) ? (ssum[g][fl] + ssum[g + 2][fl])
                                    : (sssq[g][fl] + sssq[g + 2][fl]);
        pstats[(size_t)blockIdx.x * 256 + tid] = v;
    }
}

// ---------------- reduce per-block stats -> st[256] ----------------
__global__ __launch_bounds__(256) void k_stats(const float* __restrict__ pstats,
                                               float* __restrict__ st) {
    const int o = threadIdx.x;
    const int b0 = blockIdx.x * 49;           // 16 blocks * 49 >= 782
    float s = 0.f;
    for (int b = b0; b < b0 + 49 && b < NBLK; ++b)
        s += pstats[(size_t)b * 256 + o];
    atomicAdd(&st[o], s);
}

// ---------------- BN apply + ReLU -> bf16 x cols of xy (4 elems/thread) ----------------
__global__ __launch_bounds__(256) void k_bn(
    const float* __restrict__ out, const float* __restrict__ st,
    const unsigned short* __restrict__ gamma, const unsigned short* __restrict__ beta,
    unsigned short* __restrict__ xy)
{
    const int i4 = blockIdx.x * 256 + threadIdx.x;   // grid exact: N_ENTS*DIM/4/256
    const int f0 = (i4 & 31) * 4;
    const int n = i4 >> 5;
    const float inv_n = 1.0f / (float)N_ENTS;
    const float4 o = *(const float4*)(out + (size_t)i4 * 4);
    float r[4] = {o.x, o.y, o.z, o.w};
#pragma unroll
    for (int e = 0; e < 4; ++e) {
        const int f = f0 + e;
        const float mu = st[f] * inv_n;
        const float var = st[DIM + f] * inv_n - mu * mu;
        const float g = bf2f(gamma[f]) * rsqrtf(var + BN_EPS);
        r[e] = fmaxf((r[e] - mu) * g + bf2f(beta[f]), 0.f);
    }
    uint2 w;
    w.x = pack2(r[0], r[1]);
    w.y = pack2(r[2], r[3]);
    *(uint2*)(xy + (size_t)n * KTOT + f0) = w;
}

// ---------------- scoring ----------------
__global__ __launch_bounds__(256) void k_hr(
    const int* __restrict__ head, const int* __restrict__ rel,
    const unsigned short* __restrict__ xy, const unsigned short* __restrict__ rtab,
    float* __restrict__ hr)
{
    const int wave = threadIdx.x >> 6, lane = threadIdx.x & 63;
    const int i = blockIdx.x * 4 + wave;
    const int h = head[i], r = rel[i];
    const uint hv = ((const uint*)xy)[(size_t)h * (KTOT / 2) + lane];
    const uint rv = ((const uint*)(rtab))[(size_t)r * 64 + lane];
    float2 o;
    o.x = bflo(hv) + bflo(rv);
    o.y = bfhi(hv) + bfhi(rv);
    *(float2*)(hr + (size_t)i * DIM + 2 * lane) = o;
}

// fused pos+neg scoring: w<BATCH -> pos(tail), else neg
__global__ __launch_bounds__(256) void k_score(
    const int* __restrict__ tail, const int* __restrict__ negi,
    const float* __restrict__ hr, const unsigned short* __restrict__ xy,
    void* __restrict__ outp, const int* __restrict__ flag)
{
    const int wave = threadIdx.x >> 6, lane = threadIdx.x & 63;
    const int w = blockIdx.x * 4 + wave;   // grid exact: (BATCH + BATCH*NNEG)/4
    int i, t, o;
    if (w < BATCH) { i = w; t = tail[w]; o = w; }
    else { const int w2 = w - BATCH; i = w2 >> 6; t = negi[w2]; o = w; }
    const float2 h = *(const float2*)(hr + (size_t)i * DIM + 2 * lane);
    const uint tv = ((const uint*)xy)[(size_t)t * (KTOT / 2) + lane];
    const float d0 = h.x - bflo(tv), d1 = h.y - bfhi(tv);
    float s = d0 * d0 + d1 * d1;
#pragma unroll
    for (int m = 32; m >= 1; m >>= 1) s += __shfl_xor(s, m, 64);
    if (lane == 0) {
        const float v = -sqrtf(s);
        if (flag[0]) ((unsigned short*)outp)[o] = f2bf(v);
        else         ((float*)outp)[o] = v;
    }
}

extern "C" void kernel_launch(void* const* d_in, const int* in_sizes, int n_in,
                              void* d_out, int out_size, void* d_ws, size_t ws_size,
                              hipStream_t stream)
{
    const int* head = (const int*)d_in[0];
    const int* rel  = (const int*)d_in[1];
    const int* tail = (const int*)d_in[2];
    const int* negi = (const int*)d_in[3];
    const int* eidx = (const int*)d_in[4];
    const int* etyp = (const int*)d_in[5];
    const void* ent_tab = d_in[6];
    const void* rtab_in = d_in[7];
    const void* bases_in = d_in[8];
    const void* coeffs_in = d_in[9];
    const void* wsl_in = d_in[10];
    const void* bsl_in = d_in[11];
    const void* gamma_in = d_in[12];
    const void* beta_in = d_in[13];

    char* ws = (char*)d_ws;
    size_t off = 0;
    auto alloc = [&](size_t bytes) -> char* {
        char* p = ws + off;
        off += (bytes + 511) & ~(size_t)511;
        return p;
    };
    int* flag            = (int*)alloc(4);
    int* cnt             = (int*)alloc((size_t)N_ENTS * 4);
    int* starts          = (int*)alloc((size_t)N_ENTS * 4);
    int* bsum            = (int*)alloc(391 * 4);
    int* cur             = (int*)alloc((size_t)N_ENTS * 4);
    uint* ebuf           = (uint*)alloc((size_t)NEDGE * 4);
    unsigned short* xy   = (unsigned short*)alloc((size_t)M_PAD * KTOT * 2);   // 128.1 MB
    float* outb          = (float*)alloc((size_t)N_ENTS * DIM * 4);            // 51.2 MB
    unsigned short* par  = (unsigned short*)alloc((size_t)P_TOTAL * 2);
    unsigned short* Wt   = (unsigned short*)alloc((size_t)2 * DIM * KTOT * 2); // both layers
    float* pstats        = (float*)alloc((size_t)NBLK * 256 * 4);              // 800 KB
    float* hr            = (float*)alloc((size_t)BATCH * DIM * 4);
    float* stats         = (float*)alloc(2 * 2 * DIM * 4);
    (void)ws_size; (void)in_sizes; (void)n_in; (void)out_size;

    const int* esrc = eidx;
    const int* edst = eidx + NEDGE;

    k_detect<<<1, 256, 0, stream>>>((const unsigned int*)ent_tab, flag);

    k_conv_x<<<N_ENTS * DIM / 4 / 256, 256, 0, stream>>>(ent_tab, xy, flag);
    k_conv_params<<<(P_TOTAL + 255) / 256, 256, 0, stream>>>(
        rtab_in, bases_in, coeffs_in, wsl_in, bsl_in, gamma_in, beta_in, par, flag);
    k_transw2<<<2 * KTOT * DIM / 256, 256, 0, stream>>>(par, Wt);

    hipMemsetAsync(cnt, 0, (size_t)N_ENTS * 4, stream);
    hipMemsetAsync(cur, 0, (size_t)N_ENTS * 4, stream);
    hipMemsetAsync(stats, 0, 2 * 2 * DIM * 4, stream);

    // CSR build
    k_count<<<NEDGE / 256, 256, 0, stream>>>(edst, cnt);
    k_bsum<<<391, 256, 0, stream>>>(cnt, bsum);
    k_scan1<<<1, 512, 0, stream>>>(bsum);
    k_starts<<<391, 256, 0, stream>>>(cnt, bsum, starts);
    k_fill<<<NEDGE / 256, 256, 0, stream>>>(esrc, edst, etyp, starts, cur, ebuf);

    for (int l = 0; l < 2; ++l) {
        const unsigned short* bl = par + P_BSL   + l * DIM;
        const unsigned short* cf = par + P_COEFF + l * N_RELS * NB;
        const unsigned short* gm = par + P_GAMMA + l * DIM;
        const unsigned short* bt = par + P_BETA  + l * DIM;
        const unsigned short* wt = Wt + (size_t)l * DIM * KTOT;
        float* st = stats + l * 2 * DIM;

        k_agg<<<N_ENTS / 4, 256, 0, stream>>>(ebuf, starts, cnt, cf, xy);
        k_gemm<<<NBLK, 256, 0, stream>>>(xy, wt, bl, cnt, outb, pstats);
        k_stats<<<16, 256, 0, stream>>>(pstats, st);
        k_bn<<<N_ENTS * DIM / 4 / 256, 256, 0, stream>>>(outb, st, gm, bt, xy);
    }

    k_hr<<<BATCH / 4, 256, 0, stream>>>(head, rel, xy, par + P_REL, hr);
    k_score<<<(BATCH + BATCH * NNEG) / 4, 256, 0, stream>>>(tail, negi, hr, xy, d_out, flag);
}

// Round 9
// 529.041 us; speedup vs baseline: 1.0884x; 1.0884x over previous
//
#include <hip/hip_runtime.h>
#include <stdint.h>

// Problem constants
#define N_ENTS  100000
#define M_PAD   100096          // 782 * 128
#define NTILES  6256            // M_PAD/16
#define N_RELS  16
#define DIM     128
#define NB      4
#define KTOT    640             // 128 (self) + 4*128 (bases)
#define TILE_U  10240           // ushorts per m-tile: 80*16*8
#define NEDGE   640000
#define BATCH   1024
#define NNEG    64
#define BN_EPS  1e-5f
#define NBLK    782             // M_PAD/128

// converted-parameter buffer layout (ushort offsets)
#define P_REL    0        // [16][128]
#define P_BASES  2048     // [2][4][128][128]
#define P_COEFF  133120   // [2][16][4]
#define P_WSL    133248   // [2][128][128]
#define P_BSL    166016   // [2][128]
#define P_GAMMA  166272   // [2][128]
#define P_BETA   166528   // [2][128]
#define P_TOTAL  166784

typedef unsigned int uint;
typedef short short8 __attribute__((ext_vector_type(8)));
typedef float f4 __attribute__((ext_vector_type(4)));

__device__ __forceinline__ float bf2f(unsigned short u) {
    return __uint_as_float(((unsigned int)u) << 16);
}
__device__ __forceinline__ float bflo(unsigned int u) { return __uint_as_float(u << 16); }
__device__ __forceinline__ float bfhi(unsigned int u) { return __uint_as_float(u & 0xffff0000u); }
__device__ __forceinline__ unsigned short f2bf(float f) {
    unsigned int x = __float_as_uint(f);
    x += 0x7fffu + ((x >> 16) & 1u);
    return (unsigned short)(x >> 16);
}
__device__ __forceinline__ unsigned int pack2(float a, float b) {
    return (unsigned int)f2bf(a) | ((unsigned int)f2bf(b) << 16);
}

// ---------------- dtype detection (fp32 vs bf16 storage) ----------------
__device__ __forceinline__ int bf16_like(unsigned int h) {
    unsigned int m = h & 0x7FFFu;
    return (m == 0u) || (m >= 0x2D00u && m < 0x4400u);
}
__global__ __launch_bounds__(256) void k_detect(const unsigned int* __restrict__ ent,
                                                int* __restrict__ flag) {
    __shared__ int cnt[256];
    unsigned int u = ent[threadIdx.x];
    cnt[threadIdx.x] = bf16_like(u & 0xFFFFu) & bf16_like(u >> 16);
    __syncthreads();
    for (int s = 128; s > 0; s >>= 1) {
        if (threadIdx.x < s) cnt[threadIdx.x] += cnt[threadIdx.x + s];
        __syncthreads();
    }
    if (threadIdx.x == 0) flag[0] = (cnt[0] >= 140) ? 1 : 0;
}

// ---------------- converts ----------------
__device__ __forceinline__ unsigned short cvt1(const void* src, int i, int isbf) {
    return isbf ? ((const unsigned short*)src)[i] : f2bf(((const float*)src)[i]);
}
__global__ __launch_bounds__(256) void k_conv_params(
    const void* __restrict__ rtab, const void* __restrict__ bases,
    const void* __restrict__ coeffs, const void* __restrict__ wsl,
    const void* __restrict__ bsl, const void* __restrict__ gamma,
    const void* __restrict__ beta,
    unsigned short* __restrict__ par, const int* __restrict__ flag)
{
    const int i = blockIdx.x * 256 + threadIdx.x;
    if (i >= P_TOTAL) return;
    const int isbf = flag[0];
    unsigned short v;
    if      (i < P_BASES)  v = cvt1(rtab,   i - P_REL,    isbf);
    else if (i < P_COEFF)  v = cvt1(bases,  i - P_BASES,  isbf);
    else if (i < P_WSL)    v = cvt1(coeffs, i - P_COEFF,  isbf);
    else if (i < P_BSL)    v = cvt1(wsl,    i - P_WSL,    isbf);
    else if (i < P_GAMMA)  v = cvt1(bsl,    i - P_BSL,    isbf);
    else if (i < P_BETA)   v = cvt1(gamma,  i - P_GAMMA,  isbf);
    else                   v = cvt1(beta,   i - P_BETA,   isbf);
    par[i] = v;
}

// entity -> xrow (row-major) + xyT tiled x-cols. block = one m-tile (16 rows x 16 kc)
__global__ __launch_bounds__(256) void k_conv_x(const void* __restrict__ src,
                                                unsigned short* __restrict__ xrow,
                                                unsigned short* __restrict__ xyT,
                                                const int* __restrict__ flag) {
    const int tile = blockIdx.x;                 // grid exact: 6250
    const int kc = threadIdx.x >> 4, r = threadIdx.x & 15;
    const int n = tile * 16 + r;                 // always < N_ENTS
    const size_t e0 = (size_t)n * DIM + kc * 8;
    uint4 w;
    if (flag[0]) {
        w = *(const uint4*)((const unsigned short*)src + e0);
    } else {
        const float4 f0 = *(const float4*)((const float*)src + e0);
        const float4 f1 = *(const float4*)((const float*)src + e0 + 4);
        w.x = pack2(f0.x, f0.y); w.y = pack2(f0.z, f0.w);
        w.z = pack2(f1.x, f1.y); w.w = pack2(f1.z, f1.w);
    }
    *(uint4*)(xrow + e0) = w;
    *(uint4*)(xyT + (size_t)tile * TILE_U + kc * 128 + r * 8) = w;
}

// ---------------- CSR build ----------------
__global__ __launch_bounds__(256) void k_count(const int* __restrict__ dst, int* __restrict__ cnt) {
    int e = blockIdx.x * 256 + threadIdx.x;
    if (e < NEDGE) atomicAdd(&cnt[dst[e]], 1);
}
__global__ __launch_bounds__(256) void k_bsum(const int* __restrict__ cnt, int* __restrict__ bsum) {
    __shared__ int l[256];
    int i = blockIdx.x * 256 + threadIdx.x;
    l[threadIdx.x] = (i < N_ENTS) ? cnt[i] : 0;
    __syncthreads();
    for (int s = 128; s > 0; s >>= 1) {
        if (threadIdx.x < s) l[threadIdx.x] += l[threadIdx.x + s];
        __syncthreads();
    }
    if (threadIdx.x == 0) bsum[blockIdx.x] = l[0];
}
__global__ __launch_bounds__(512) void k_scan1(int* __restrict__ bsum) {
    __shared__ int tmp[512];
    const int t = threadIdx.x;
    const int v = (t < 391) ? bsum[t] : 0;
    tmp[t] = v;
    __syncthreads();
    for (int off = 1; off < 512; off <<= 1) {
        int u = (t >= off) ? tmp[t - off] : 0;
        __syncthreads();
        tmp[t] += u;
        __syncthreads();
    }
    if (t < 391) bsum[t] = tmp[t] - v;
}
__global__ __launch_bounds__(256) void k_starts(const int* __restrict__ cnt,
                                                const int* __restrict__ boff,
                                                int* __restrict__ starts) {
    __shared__ int tmp[256];
    const int t = threadIdx.x;
    const int i = blockIdx.x * 256 + t;
    const int v = (i < N_ENTS) ? cnt[i] : 0;
    tmp[t] = v;
    __syncthreads();
    for (int off = 1; off < 256; off <<= 1) {
        int u = (t >= off) ? tmp[t - off] : 0;
        __syncthreads();
        tmp[t] += u;
        __syncthreads();
    }
    if (i < N_ENTS) starts[i] = tmp[t] - v + boff[blockIdx.x];
}
__global__ __launch_bounds__(256) void k_fill(const int* __restrict__ src, const int* __restrict__ dst,
                                              const int* __restrict__ et, const int* __restrict__ starts,
                                              int* __restrict__ cur, uint* __restrict__ ebuf) {
    int e = blockIdx.x * 256 + threadIdx.x;
    if (e >= NEDGE) return;
    const int d = dst[e];
    const int p = atomicAdd(&cur[d], 1);
    ebuf[starts[d] + p] = (uint)src[e] | ((uint)et[e] << 20);
}

// ---------------- edge aggregation: gather xrow, write y into xyT tiled chunks ----------------
__global__ __launch_bounds__(256) void k_agg(
    const uint* __restrict__ ebuf, const int* __restrict__ starts, const int* __restrict__ cnt,
    const unsigned short* __restrict__ coeffs, const unsigned short* __restrict__ xrow,
    unsigned short* __restrict__ xyT)
{
    __shared__ uint2 scf[16];
    if (threadIdx.x < 16) scf[threadIdx.x] = *(const uint2*)(coeffs + threadIdx.x * 4);
    __syncthreads();
    const int wave = threadIdx.x >> 6, lane = threadIdx.x & 63;
    const int n = blockIdx.x * 4 + wave;   // grid exact: N_ENTS/4
    const int c0 = starts[n], cn = cnt[n];
    const int q = (cn + 3) >> 2;
    float lo[4][NB] = {}, hi[4][NB] = {};
    const uint* __restrict__ x32 = (const uint*)xrow;
    for (int i = 0; i < q; ++i) {
        uint rec[4];
        int valid[4];
#pragma unroll
        for (int s = 0; s < 4; ++s) {
            const int p = s * q + i;
            valid[s] = p < cn;
            rec[s] = ebuf[c0 + (valid[s] ? p : 0)];
        }
        uint xw[4];
#pragma unroll
        for (int s = 0; s < 4; ++s)
            xw[s] = x32[(size_t)(rec[s] & 0xFFFFFu) * 64 + lane];
#pragma unroll
        for (int s = 0; s < 4; ++s) {
            uint2 cc = scf[rec[s] >> 20];
            if (!valid[s]) { cc.x = 0; cc.y = 0; }
            const float cb[NB] = {bflo(cc.x), bfhi(cc.x), bflo(cc.y), bfhi(cc.y)};
            const float xl = bflo(xw[s]), xh = bfhi(xw[s]);
#pragma unroll
            for (int b = 0; b < NB; ++b) {
                lo[s][b] = fmaf(cb[b], xl, lo[s][b]);
                hi[s][b] = fmaf(cb[b], xh, hi[s][b]);
            }
        }
    }
    // lane holds y_b[2*lane], y_b[2*lane+1]; tiled dest: chunk kc=16+b*16+(lane>>2),
    // slot r=n&15, uint elem (lane&3)
    const size_t tb = (size_t)(n >> 4) * TILE_U + (n & 15) * 8;
#pragma unroll
    for (int b = 0; b < NB; ++b) {
        const float l = (lo[0][b] + lo[1][b]) + (lo[2][b] + lo[3][b]);
        const float h = (hi[0][b] + hi[1][b]) + (hi[2][b] + hi[3][b]);
        *(uint*)(xyT + tb + (size_t)(16 + b * 16 + (lane >> 2)) * 128 + (lane & 3) * 2) = pack2(l, h);
    }
}

// ---------------- build WtT tiled for BOTH layers: [l][jt 8][kc 80][r 16][8] ----------------
__global__ __launch_bounds__(256) void k_transw2(const unsigned short* __restrict__ par,
                                                 unsigned short* __restrict__ WtT) {
    const int i = blockIdx.x * 256 + threadIdx.x;   // grid exact: 20480/256 = 80
    const int l = i / 10240;
    const int rem = i - l * 10240;
    const int jt2 = rem / 1280;
    const int rem2 = rem - jt2 * 1280;
    const int kc = rem2 >> 4, r = rem2 & 15;
    const int n = jt2 * 16 + r;
    unsigned short v[8];
#pragma unroll
    for (int e = 0; e < 8; ++e) {
        const int k = kc * 8 + e;
        v[e] = (k < DIM)
            ? par[P_WSL + l * DIM * DIM + k * DIM + n]
            : par[P_BASES + l * NB * DIM * DIM + (k - DIM) * DIM + n];
    }
    *(uint4*)(WtT + (size_t)l * 81920 + (size_t)jt2 * TILE_U + (size_t)kc * 128 + r * 8) = *(uint4*)v;
}

// ---------------- tiled MFMA GEMM, named-register double buffer, no barriers ----------------
// token-pasting macros: P is the buffer letter (x or y)
#define LDSET(P, s) \
    P##a0 = *(const short8*)(pA0 + (s) * 512); \
    P##a1 = *(const short8*)(pA1 + (s) * 512); \
    P##a2 = *(const short8*)(pA2 + (s) * 512); \
    P##a3 = *(const short8*)(pA3 + (s) * 512); \
    P##b0 = *(const short8*)(pB0 + (s) * 512); \
    P##b1 = *(const short8*)(pB1 + (s) * 512); \
    P##b2 = *(const short8*)(pB2 + (s) * 512); \
    P##b3 = *(const short8*)(pB3 + (s) * 512);

#define MMSET(P) \
    acc[0][0] = __builtin_amdgcn_mfma_f32_16x16x32_bf16(P##a0, P##b0, acc[0][0], 0, 0, 0); \
    acc[0][1] = __builtin_amdgcn_mfma_f32_16x16x32_bf16(P##a0, P##b1, acc[0][1], 0, 0, 0); \
    acc[0][2] = __builtin_amdgcn_mfma_f32_16x16x32_bf16(P##a0, P##b2, acc[0][2], 0, 0, 0); \
    acc[0][3] = __builtin_amdgcn_mfma_f32_16x16x32_bf16(P##a0, P##b3, acc[0][3], 0, 0, 0); \
    acc[1][0] = __builtin_amdgcn_mfma_f32_16x16x32_bf16(P##a1, P##b0, acc[1][0], 0, 0, 0); \
    acc[1][1] = __builtin_amdgcn_mfma_f32_16x16x32_bf16(P##a1, P##b1, acc[1][1], 0, 0, 0); \
    acc[1][2] = __builtin_amdgcn_mfma_f32_16x16x32_bf16(P##a1, P##b2, acc[1][2], 0, 0, 0); \
    acc[1][3] = __builtin_amdgcn_mfma_f32_16x16x32_bf16(P##a1, P##b3, acc[1][3], 0, 0, 0); \
    acc[2][0] = __builtin_amdgcn_mfma_f32_16x16x32_bf16(P##a2, P##b0, acc[2][0], 0, 0, 0); \
    acc[2][1] = __builtin_amdgcn_mfma_f32_16x16x32_bf16(P##a2, P##b1, acc[2][1], 0, 0, 0); \
    acc[2][2] = __builtin_amdgcn_mfma_f32_16x16x32_bf16(P##a2, P##b2, acc[2][2], 0, 0, 0); \
    acc[2][3] = __builtin_amdgcn_mfma_f32_16x16x32_bf16(P##a2, P##b3, acc[2][3], 0, 0, 0); \
    acc[3][0] = __builtin_amdgcn_mfma_f32_16x16x32_bf16(P##a3, P##b0, acc[3][0], 0, 0, 0); \
    acc[3][1] = __builtin_amdgcn_mfma_f32_16x16x32_bf16(P##a3, P##b1, acc[3][1], 0, 0, 0); \
    acc[3][2] = __builtin_amdgcn_mfma_f32_16x16x32_bf16(P##a3, P##b2, acc[3][2], 0, 0, 0); \
    acc[3][3] = __builtin_amdgcn_mfma_f32_16x16x32_bf16(P##a3, P##b3, acc[3][3], 0, 0, 0);

__global__ __launch_bounds__(256) void k_gemm(
    const unsigned short* __restrict__ xyT, const unsigned short* __restrict__ wtT,
    const unsigned short* __restrict__ bsl, const int* __restrict__ cnt,
    unsigned short* __restrict__ out, float* __restrict__ pstats)
{
    const int tid = threadIdx.x;
    const int wave = tid >> 6, lane = tid & 63;
    const int quad = lane >> 4, l16 = lane & 15;
    const int m0 = blockIdx.x * 128;
    const int rbase = (wave >> 1) * 64;
    const int col0 = (wave & 1) * 64;

    // fragment pointers: contiguous 1KB per wave-load
    const int gmt = blockIdx.x * 8 + (wave >> 1) * 4;
    const unsigned short* pA0 = xyT + (size_t)(gmt + 0) * TILE_U + quad * 128 + l16 * 8;
    const unsigned short* pA1 = xyT + (size_t)(gmt + 1) * TILE_U + quad * 128 + l16 * 8;
    const unsigned short* pA2 = xyT + (size_t)(gmt + 2) * TILE_U + quad * 128 + l16 * 8;
    const unsigned short* pA3 = xyT + (size_t)(gmt + 3) * TILE_U + quad * 128 + l16 * 8;
    const int jt0 = (wave & 1) * 4;
    const unsigned short* pB0 = wtT + (size_t)(jt0 + 0) * TILE_U + quad * 128 + l16 * 8;
    const unsigned short* pB1 = wtT + (size_t)(jt0 + 1) * TILE_U + quad * 128 + l16 * 8;
    const unsigned short* pB2 = wtT + (size_t)(jt0 + 2) * TILE_U + quad * 128 + l16 * 8;
    const unsigned short* pB3 = wtT + (size_t)(jt0 + 3) * TILE_U + quad * 128 + l16 * 8;

    f4 acc[4][4];
#pragma unroll
    for (int i = 0; i < 4; ++i)
#pragma unroll
        for (int j = 0; j < 4; ++j)
#pragma unroll
            for (int r = 0; r < 4; ++r) acc[i][j][r] = 0.f;

    short8 xa0, xa1, xa2, xa3, xb0, xb1, xb2, xb3;
    short8 ya0, ya1, ya2, ya3, yb0, yb1, yb2, yb3;

    LDSET(x, 0)
    LDSET(y, 1)  MMSET(x)
    LDSET(x, 2)  MMSET(y)
    LDSET(y, 3)  MMSET(x)
    LDSET(x, 4)  MMSET(y)
    LDSET(y, 5)  MMSET(x)
    LDSET(x, 6)  MMSET(y)
    LDSET(y, 7)  MMSET(x)
    LDSET(x, 8)  MMSET(y)
    LDSET(y, 9)  MMSET(x)
    LDSET(x, 10) MMSET(y)
    LDSET(y, 11) MMSET(x)
    LDSET(x, 12) MMSET(y)
    LDSET(y, 13) MMSET(x)
    LDSET(x, 14) MMSET(y)
    LDSET(y, 15) MMSET(x)
    LDSET(x, 16) MMSET(y)
    LDSET(y, 17) MMSET(x)
    LDSET(x, 18) MMSET(y)
    LDSET(y, 19) MMSET(x)
    MMSET(y)

    // epilogue: o = (acc + bias)/deg ; store bf16 ; block-local BN stats
    float s_sum[4] = {0, 0, 0, 0}, s_ssq[4] = {0, 0, 0, 0};
#pragma unroll
    for (int i = 0; i < 4; ++i) {
#pragma unroll
        for (int r = 0; r < 4; ++r) {
            const int row = m0 + rbase + i * 16 + quad * 4 + r;
            const int rc = row < N_ENTS ? row : N_ENTS - 1;
            const float rdeg = 1.0f / fmaxf((float)cnt[rc], 1.0f);
            const bool valid = row < N_ENTS;
#pragma unroll
            for (int j = 0; j < 4; ++j) {
                const int f = col0 + j * 16 + l16;
                const float o = (acc[i][j][r] + bf2f(bsl[f])) * rdeg;
                if (valid) {
                    out[(size_t)row * DIM + f] = f2bf(o);
                    s_sum[j] += o;
                    s_ssq[j] += o * o;
                }
            }
        }
    }
    __shared__ float ssum[4][64], sssq[4][64];
#pragma unroll
    for (int j = 0; j < 4; ++j) {
        float s = s_sum[j], q2 = s_ssq[j];
        s += __shfl_xor(s, 16, 64); s += __shfl_xor(s, 32, 64);
        q2 += __shfl_xor(q2, 16, 64); q2 += __shfl_xor(q2, 32, 64);
        if (quad == 0) {
            ssum[wave][j * 16 + l16] = s;
            sssq[wave][j * 16 + l16] = q2;
        }
    }
    __syncthreads();
    {
        const int f = tid & 127;
        const int g = f >> 6;
        const int fl = f & 63;
        const float v = (tid < 128) ? (ssum[g][fl] + ssum[g + 2][fl])
                                    : (sssq[g][fl] + sssq[g + 2][fl]);
        pstats[(size_t)blockIdx.x * 256 + tid] = v;
    }
}

// ---------------- reduce per-block stats -> st[256] ----------------
__global__ __launch_bounds__(256) void k_stats(const float* __restrict__ pstats,
                                               float* __restrict__ st) {
    const int o = threadIdx.x;
    const int b0 = blockIdx.x * 49;
    float s = 0.f;
    for (int b = b0; b < b0 + 49 && b < NBLK; ++b)
        s += pstats[(size_t)b * 256 + o];
    atomicAdd(&st[o], s);
}

// ---------------- BN apply + ReLU: outb(bf16) -> xrow (+ xyT x-cols if l==0) ----------------
__global__ __launch_bounds__(256) void k_bn(
    const unsigned short* __restrict__ out, const float* __restrict__ st,
    const unsigned short* __restrict__ gamma, const unsigned short* __restrict__ beta,
    unsigned short* __restrict__ xrow, unsigned short* __restrict__ xyT, int writeTiled)
{
    const int tile = blockIdx.x;                 // grid exact: 6250
    const int kc = threadIdx.x >> 4, r = threadIdx.x & 15;
    const int n = tile * 16 + r;
    const size_t e0 = (size_t)n * DIM + kc * 8;
    const uint4 u = *(const uint4*)(out + e0);
    const uint uu[4] = {u.x, u.y, u.z, u.w};
    const float inv_n = 1.0f / (float)N_ENTS;
    uint w[4];
#pragma unroll
    for (int p = 0; p < 4; ++p) {
        const int f0 = kc * 8 + p * 2;
        float v0 = bflo(uu[p]), v1 = bfhi(uu[p]);
        const float mu0 = st[f0] * inv_n, mu1 = st[f0 + 1] * inv_n;
        const float var0 = st[DIM + f0] * inv_n - mu0 * mu0;
        const float var1 = st[DIM + f0 + 1] * inv_n - mu1 * mu1;
        const float g0 = bf2f(gamma[f0]) * rsqrtf(var0 + BN_EPS);
        const float g1 = bf2f(gamma[f0 + 1]) * rsqrtf(var1 + BN_EPS);
        v0 = fmaxf((v0 - mu0) * g0 + bf2f(beta[f0]), 0.f);
        v1 = fmaxf((v1 - mu1) * g1 + bf2f(beta[f0 + 1]), 0.f);
        w[p] = pack2(v0, v1);
    }
    uint4 wv = {w[0], w[1], w[2], w[3]};
    *(uint4*)(xrow + e0) = wv;
    if (writeTiled)
        *(uint4*)(xyT + (size_t)tile * TILE_U + kc * 128 + r * 8) = wv;
}

// ---------------- scoring ----------------
__global__ __launch_bounds__(256) void k_hr(
    const int* __restrict__ head, const int* __restrict__ rel,
    const unsigned short* __restrict__ xrow, const unsigned short* __restrict__ rtab,
    float* __restrict__ hr)
{
    const int wave = threadIdx.x >> 6, lane = threadIdx.x & 63;
    const int i = blockIdx.x * 4 + wave;
    const int h = head[i], r = rel[i];
    const uint hv = ((const uint*)xrow)[(size_t)h * 64 + lane];
    const uint rv = ((const uint*)rtab)[(size_t)r * 64 + lane];
    float2 o;
    o.x = bflo(hv) + bflo(rv);
    o.y = bfhi(hv) + bfhi(rv);
    *(float2*)(hr + (size_t)i * DIM + 2 * lane) = o;
}

__global__ __launch_bounds__(256) void k_score(
    const int* __restrict__ tail, const int* __restrict__ negi,
    const float* __restrict__ hr, const unsigned short* __restrict__ xrow,
    void* __restrict__ outp, const int* __restrict__ flag)
{
    const int wave = threadIdx.x >> 6, lane = threadIdx.x & 63;
    const int w = blockIdx.x * 4 + wave;
    int i, t, o;
    if (w < BATCH) { i = w; t = tail[w]; o = w; }
    else { const int w2 = w - BATCH; i = w2 >> 6; t = negi[w2]; o = w; }
    const float2 h = *(const float2*)(hr + (size_t)i * DIM + 2 * lane);
    const uint tv = ((const uint*)xrow)[(size_t)t * 64 + lane];
    const float d0 = h.x - bflo(tv), d1 = h.y - bfhi(tv);
    float s = d0 * d0 + d1 * d1;
#pragma unroll
    for (int m = 32; m >= 1; m >>= 1) s += __shfl_xor(s, m, 64);
    if (lane == 0) {
        const float v = -sqrtf(s);
        if (flag[0]) ((unsigned short*)outp)[o] = f2bf(v);
        else         ((float*)outp)[o] = v;
    }
}

extern "C" void kernel_launch(void* const* d_in, const int* in_sizes, int n_in,
                              void* d_out, int out_size, void* d_ws, size_t ws_size,
                              hipStream_t stream)
{
    const int* head = (const int*)d_in[0];
    const int* rel  = (const int*)d_in[1];
    const int* tail = (const int*)d_in[2];
    const int* negi = (const int*)d_in[3];
    const int* eidx = (const int*)d_in[4];
    const int* etyp = (const int*)d_in[5];
    const void* ent_tab = d_in[6];
    const void* rtab_in = d_in[7];
    const void* bases_in = d_in[8];
    const void* coeffs_in = d_in[9];
    const void* wsl_in = d_in[10];
    const void* bsl_in = d_in[11];
    const void* gamma_in = d_in[12];
    const void* beta_in = d_in[13];

    char* ws = (char*)d_ws;
    size_t off = 0;
    auto alloc = [&](size_t bytes) -> char* {
        char* p = ws + off;
        off += (bytes + 511) & ~(size_t)511;
        return p;
    };
    int* flag            = (int*)alloc(4);
    int* cnt             = (int*)alloc((size_t)N_ENTS * 4);
    int* starts          = (int*)alloc((size_t)N_ENTS * 4);
    int* bsum            = (int*)alloc(391 * 4);
    int* cur             = (int*)alloc((size_t)N_ENTS * 4);
    uint* ebuf           = (uint*)alloc((size_t)NEDGE * 4);
    unsigned short* xyT  = (unsigned short*)alloc((size_t)NTILES * TILE_U * 2); // 128.1 MB tiled
    unsigned short* xrow = (unsigned short*)alloc((size_t)N_ENTS * DIM * 2);    // 25.6 MB row-major
    unsigned short* outb = (unsigned short*)alloc((size_t)M_PAD * DIM * 2);     // 25.6 MB bf16
    unsigned short* par  = (unsigned short*)alloc((size_t)P_TOTAL * 2);
    unsigned short* WtT  = (unsigned short*)alloc((size_t)2 * 81920 * 2);
    float* pstats        = (float*)alloc((size_t)NBLK * 256 * 4);
    float* hr            = (float*)alloc((size_t)BATCH * DIM * 4);
    float* stats         = (float*)alloc(2 * 2 * DIM * 4);
    (void)ws_size; (void)in_sizes; (void)n_in; (void)out_size;

    const int* esrc = eidx;
    const int* edst = eidx + NEDGE;

    k_detect<<<1, 256, 0, stream>>>((const unsigned int*)ent_tab, flag);

    k_conv_x<<<N_ENTS / 16, 256, 0, stream>>>(ent_tab, xrow, xyT, flag);
    k_conv_params<<<(P_TOTAL + 255) / 256, 256, 0, stream>>>(
        rtab_in, bases_in, coeffs_in, wsl_in, bsl_in, gamma_in, beta_in, par, flag);
    k_transw2<<<80, 256, 0, stream>>>(par, WtT);

    hipMemsetAsync(cnt, 0, (size_t)N_ENTS * 4, stream);
    hipMemsetAsync(cur, 0, (size_t)N_ENTS * 4, stream);
    hipMemsetAsync(stats, 0, 2 * 2 * DIM * 4, stream);

    k_count<<<NEDGE / 256, 256, 0, stream>>>(edst, cnt);
    k_bsum<<<391, 256, 0, stream>>>(cnt, bsum);
    k_scan1<<<1, 512, 0, stream>>>(bsum);
    k_starts<<<391, 256, 0, stream>>>(cnt, bsum, starts);
    k_fill<<<NEDGE / 256, 256, 0, stream>>>(esrc, edst, etyp, starts, cur, ebuf);

    for (int l = 0; l < 2; ++l) {
        const unsigned short* bl = par + P_BSL   + l * DIM;
        const unsigned short* cf = par + P_COEFF + l * N_RELS * NB;
        const unsigned short* gm = par + P_GAMMA + l * DIM;
        const unsigned short* bt = par + P_BETA  + l * DIM;
        const unsigned short* wt = WtT + (size_t)l * 81920;
        float* st = stats + l * 2 * DIM;

        k_agg<<<N_ENTS / 4, 256, 0, stream>>>(ebuf, starts, cnt, cf, xrow, xyT);
        k_gemm<<<NBLK, 256, 0, stream>>>(xyT, wt, bl, cnt, outb, pstats);
        k_stats<<<16, 256, 0, stream>>>(pstats, st);
        k_bn<<<N_ENTS / 16, 256, 0, stream>>>(outb, st, gm, bt, xrow, xyT, l == 0 ? 1 : 0);
    }

    k_hr<<<BATCH / 4, 256, 0, stream>>>(head, rel, xrow, par + P_REL, hr);
    k_score<<<(BATCH + BATCH * NNEG) / 4, 256, 0, stream>>>(tail, negi, hr, xrow, d_out, flag);
}

// Round 10
// 494.012 us; speedup vs baseline: 1.1656x; 1.0709x over previous
//
#include <hip/hip_runtime.h>
#include <stdint.h>

// Problem constants
#define N_ENTS  100000
#define M_PAD   100096          // 782 * 128
#define NTILES  6256            // M_PAD/16
#define N_RELS  16
#define DIM     128
#define NB      4
#define KTOT    640             // 128 (self) + 4*128 (bases)
#define TILE_U  10240           // ushorts per m-tile: 80*16*8
#define NEDGE   640000
#define BATCH   1024
#define NNEG    64
#define BN_EPS  1e-5f
#define NBLK    782             // M_PAD/128

// converted-parameter buffer layout (ushort offsets)
#define P_REL    0        // [16][128]
#define P_BASES  2048     // [2][4][128][128]
#define P_COEFF  133120   // [2][16][4]
#define P_WSL    133248   // [2][128][128]
#define P_BSL    166016   // [2][128]
#define P_GAMMA  166272   // [2][128]
#define P_BETA   166528   // [2][128]
#define P_TOTAL  166784

typedef unsigned int uint;
typedef short short8 __attribute__((ext_vector_type(8)));
typedef float f4 __attribute__((ext_vector_type(4)));

__device__ __forceinline__ float bf2f(unsigned short u) {
    return __uint_as_float(((unsigned int)u) << 16);
}
__device__ __forceinline__ float bflo(unsigned int u) { return __uint_as_float(u << 16); }
__device__ __forceinline__ float bfhi(unsigned int u) { return __uint_as_float(u & 0xffff0000u); }
__device__ __forceinline__ unsigned short f2bf(float f) {
    unsigned int x = __float_as_uint(f);
    x += 0x7fffu + ((x >> 16) & 1u);
    return (unsigned short)(x >> 16);
}
__device__ __forceinline__ unsigned int pack2(float a, float b) {
    return (unsigned int)f2bf(a) | ((unsigned int)f2bf(b) << 16);
}

// ---------------- dtype detection (fp32 vs bf16 storage) ----------------
__device__ __forceinline__ int bf16_like(unsigned int h) {
    unsigned int m = h & 0x7FFFu;
    return (m == 0u) || (m >= 0x2D00u && m < 0x4400u);
}
__global__ __launch_bounds__(256) void k_detect(const unsigned int* __restrict__ ent,
                                                int* __restrict__ flag) {
    __shared__ int cnt[256];
    unsigned int u = ent[threadIdx.x];
    cnt[threadIdx.x] = bf16_like(u & 0xFFFFu) & bf16_like(u >> 16);
    __syncthreads();
    for (int s = 128; s > 0; s >>= 1) {
        if (threadIdx.x < s) cnt[threadIdx.x] += cnt[threadIdx.x + s];
        __syncthreads();
    }
    if (threadIdx.x == 0) flag[0] = (cnt[0] >= 140) ? 1 : 0;
}

// ---------------- converts ----------------
__device__ __forceinline__ unsigned short cvt1(const void* src, int i, int isbf) {
    return isbf ? ((const unsigned short*)src)[i] : f2bf(((const float*)src)[i]);
}
__global__ __launch_bounds__(256) void k_conv_params(
    const void* __restrict__ rtab, const void* __restrict__ bases,
    const void* __restrict__ coeffs, const void* __restrict__ wsl,
    const void* __restrict__ bsl, const void* __restrict__ gamma,
    const void* __restrict__ beta,
    unsigned short* __restrict__ par, const int* __restrict__ flag)
{
    const int i = blockIdx.x * 256 + threadIdx.x;
    if (i >= P_TOTAL) return;
    const int isbf = flag[0];
    unsigned short v;
    if      (i < P_BASES)  v = cvt1(rtab,   i - P_REL,    isbf);
    else if (i < P_COEFF)  v = cvt1(bases,  i - P_BASES,  isbf);
    else if (i < P_WSL)    v = cvt1(coeffs, i - P_COEFF,  isbf);
    else if (i < P_BSL)    v = cvt1(wsl,    i - P_WSL,    isbf);
    else if (i < P_GAMMA)  v = cvt1(bsl,    i - P_BSL,    isbf);
    else if (i < P_BETA)   v = cvt1(gamma,  i - P_GAMMA,  isbf);
    else                   v = cvt1(beta,   i - P_BETA,   isbf);
    par[i] = v;
}

// entity -> xrow (row-major) + xyT tiled x-cols. block = one m-tile (16 rows x 16 kc)
__global__ __launch_bounds__(256) void k_conv_x(const void* __restrict__ src,
                                                unsigned short* __restrict__ xrow,
                                                unsigned short* __restrict__ xyT,
                                                const int* __restrict__ flag) {
    const int tile = blockIdx.x;                 // grid exact: 6250
    const int kc = threadIdx.x >> 4, r = threadIdx.x & 15;
    const int n = tile * 16 + r;                 // always < N_ENTS
    const size_t e0 = (size_t)n * DIM + kc * 8;
    uint4 w;
    if (flag[0]) {
        w = *(const uint4*)((const unsigned short*)src + e0);
    } else {
        const float4 f0 = *(const float4*)((const float*)src + e0);
        const float4 f1 = *(const float4*)((const float*)src + e0 + 4);
        w.x = pack2(f0.x, f0.y); w.y = pack2(f0.z, f0.w);
        w.z = pack2(f1.x, f1.y); w.w = pack2(f1.z, f1.w);
    }
    *(uint4*)(xrow + e0) = w;
    *(uint4*)(xyT + (size_t)tile * TILE_U + kc * 128 + r * 8) = w;
}

// ---------------- CSR build ----------------
__global__ __launch_bounds__(256) void k_count(const int* __restrict__ dst, int* __restrict__ cnt) {
    int e = blockIdx.x * 256 + threadIdx.x;
    if (e < NEDGE) atomicAdd(&cnt[dst[e]], 1);
}
__global__ __launch_bounds__(256) void k_bsum(const int* __restrict__ cnt, int* __restrict__ bsum) {
    __shared__ int l[256];
    int i = blockIdx.x * 256 + threadIdx.x;
    l[threadIdx.x] = (i < N_ENTS) ? cnt[i] : 0;
    __syncthreads();
    for (int s = 128; s > 0; s >>= 1) {
        if (threadIdx.x < s) l[threadIdx.x] += l[threadIdx.x + s];
        __syncthreads();
    }
    if (threadIdx.x == 0) bsum[blockIdx.x] = l[0];
}
__global__ __launch_bounds__(512) void k_scan1(int* __restrict__ bsum) {
    __shared__ int tmp[512];
    const int t = threadIdx.x;
    const int v = (t < 391) ? bsum[t] : 0;
    tmp[t] = v;
    __syncthreads();
    for (int off = 1; off < 512; off <<= 1) {
        int u = (t >= off) ? tmp[t - off] : 0;
        __syncthreads();
        tmp[t] += u;
        __syncthreads();
    }
    if (t < 391) bsum[t] = tmp[t] - v;
}
__global__ __launch_bounds__(256) void k_starts(const int* __restrict__ cnt,
                                                const int* __restrict__ boff,
                                                int* __restrict__ starts) {
    __shared__ int tmp[256];
    const int t = threadIdx.x;
    const int i = blockIdx.x * 256 + t;
    const int v = (i < N_ENTS) ? cnt[i] : 0;
    tmp[t] = v;
    __syncthreads();
    for (int off = 1; off < 256; off <<= 1) {
        int u = (t >= off) ? tmp[t - off] : 0;
        __syncthreads();
        tmp[t] += u;
        __syncthreads();
    }
    if (i < N_ENTS) starts[i] = tmp[t] - v + boff[blockIdx.x];
}
__global__ __launch_bounds__(256) void k_fill(const int* __restrict__ src, const int* __restrict__ dst,
                                              const int* __restrict__ et, const int* __restrict__ starts,
                                              int* __restrict__ cur, uint* __restrict__ ebuf) {
    int e = blockIdx.x * 256 + threadIdx.x;
    if (e >= NEDGE) return;
    const int d = dst[e];
    const int p = atomicAdd(&cur[d], 1);
    ebuf[starts[d] + p] = (uint)src[e] | ((uint)et[e] << 20);
}

// ---------------- edge aggregation: gather xrow, write y into xyT tiled chunks ----------------
__global__ __launch_bounds__(256) void k_agg(
    const uint* __restrict__ ebuf, const int* __restrict__ starts, const int* __restrict__ cnt,
    const unsigned short* __restrict__ coeffs, const unsigned short* __restrict__ xrow,
    unsigned short* __restrict__ xyT)
{
    __shared__ uint2 scf[16];
    if (threadIdx.x < 16) scf[threadIdx.x] = *(const uint2*)(coeffs + threadIdx.x * 4);
    __syncthreads();
    const int wave = threadIdx.x >> 6, lane = threadIdx.x & 63;
    const int n = blockIdx.x * 4 + wave;   // grid exact: N_ENTS/4
    const int c0 = starts[n], cn = cnt[n];
    const int q = (cn + 3) >> 2;
    float lo[4][NB] = {}, hi[4][NB] = {};
    const uint* __restrict__ x32 = (const uint*)xrow;
    for (int i = 0; i < q; ++i) {
        uint rec[4];
        int valid[4];
#pragma unroll
        for (int s = 0; s < 4; ++s) {
            const int p = s * q + i;
            valid[s] = p < cn;
            rec[s] = ebuf[c0 + (valid[s] ? p : 0)];
        }
        uint xw[4];
#pragma unroll
        for (int s = 0; s < 4; ++s)
            xw[s] = x32[(size_t)(rec[s] & 0xFFFFFu) * 64 + lane];
#pragma unroll
        for (int s = 0; s < 4; ++s) {
            uint2 cc = scf[rec[s] >> 20];
            if (!valid[s]) { cc.x = 0; cc.y = 0; }
            const float cb[NB] = {bflo(cc.x), bfhi(cc.x), bflo(cc.y), bfhi(cc.y)};
            const float xl = bflo(xw[s]), xh = bfhi(xw[s]);
#pragma unroll
            for (int b = 0; b < NB; ++b) {
                lo[s][b] = fmaf(cb[b], xl, lo[s][b]);
                hi[s][b] = fmaf(cb[b], xh, hi[s][b]);
            }
        }
    }
    const size_t tb = (size_t)(n >> 4) * TILE_U + (n & 15) * 8;
#pragma unroll
    for (int b = 0; b < NB; ++b) {
        const float l = (lo[0][b] + lo[1][b]) + (lo[2][b] + lo[3][b]);
        const float h = (hi[0][b] + hi[1][b]) + (hi[2][b] + hi[3][b]);
        *(uint*)(xyT + tb + (size_t)(16 + b * 16 + (lane >> 2)) * 128 + (lane & 3) * 2) = pack2(l, h);
    }
}

// ---------------- build WtT tiled for BOTH layers: [l][jt 8][kc 80][r 16][8] ----------------
__global__ __launch_bounds__(256) void k_transw2(const unsigned short* __restrict__ par,
                                                 unsigned short* __restrict__ WtT) {
    const int i = blockIdx.x * 256 + threadIdx.x;   // grid exact: 20480/256 = 80
    const int l = i / 10240;
    const int rem = i - l * 10240;
    const int jt2 = rem / 1280;
    const int rem2 = rem - jt2 * 1280;
    const int kc = rem2 >> 4, r = rem2 & 15;
    const int n = jt2 * 16 + r;
    unsigned short v[8];
#pragma unroll
    for (int e = 0; e < 8; ++e) {
        const int k = kc * 8 + e;
        v[e] = (k < DIM)
            ? par[P_WSL + l * DIM * DIM + k * DIM + n]
            : par[P_BASES + l * NB * DIM * DIM + (k - DIM) * DIM + n];
    }
    *(uint4*)(WtT + (size_t)l * 81920 + (size_t)jt2 * TILE_U + (size_t)kc * 128 + r * 8) = *(uint4*)v;
}

// ---------------- tiled MFMA GEMM, named-register double buffer + sched groups ----------------
#define LDSET(P, s) \
    P##a0 = *(const short8*)(pA0 + (s) * 512); \
    P##a1 = *(const short8*)(pA1 + (s) * 512); \
    P##a2 = *(const short8*)(pA2 + (s) * 512); \
    P##a3 = *(const short8*)(pA3 + (s) * 512); \
    P##b0 = *(const short8*)(pB0 + (s) * 512); \
    P##b1 = *(const short8*)(pB1 + (s) * 512); \
    P##b2 = *(const short8*)(pB2 + (s) * 512); \
    P##b3 = *(const short8*)(pB3 + (s) * 512);

#define MMSET(P) \
    acc[0][0] = __builtin_amdgcn_mfma_f32_16x16x32_bf16(P##a0, P##b0, acc[0][0], 0, 0, 0); \
    acc[0][1] = __builtin_amdgcn_mfma_f32_16x16x32_bf16(P##a0, P##b1, acc[0][1], 0, 0, 0); \
    acc[0][2] = __builtin_amdgcn_mfma_f32_16x16x32_bf16(P##a0, P##b2, acc[0][2], 0, 0, 0); \
    acc[0][3] = __builtin_amdgcn_mfma_f32_16x16x32_bf16(P##a0, P##b3, acc[0][3], 0, 0, 0); \
    acc[1][0] = __builtin_amdgcn_mfma_f32_16x16x32_bf16(P##a1, P##b0, acc[1][0], 0, 0, 0); \
    acc[1][1] = __builtin_amdgcn_mfma_f32_16x16x32_bf16(P##a1, P##b1, acc[1][1], 0, 0, 0); \
    acc[1][2] = __builtin_amdgcn_mfma_f32_16x16x32_bf16(P##a1, P##b2, acc[1][2], 0, 0, 0); \
    acc[1][3] = __builtin_amdgcn_mfma_f32_16x16x32_bf16(P##a1, P##b3, acc[1][3], 0, 0, 0); \
    acc[2][0] = __builtin_amdgcn_mfma_f32_16x16x32_bf16(P##a2, P##b0, acc[2][0], 0, 0, 0); \
    acc[2][1] = __builtin_amdgcn_mfma_f32_16x16x32_bf16(P##a2, P##b1, acc[2][1], 0, 0, 0); \
    acc[2][2] = __builtin_amdgcn_mfma_f32_16x16x32_bf16(P##a2, P##b2, acc[2][2], 0, 0, 0); \
    acc[2][3] = __builtin_amdgcn_mfma_f32_16x16x32_bf16(P##a2, P##b3, acc[2][3], 0, 0, 0); \
    acc[3][0] = __builtin_amdgcn_mfma_f32_16x16x32_bf16(P##a3, P##b0, acc[3][0], 0, 0, 0); \
    acc[3][1] = __builtin_amdgcn_mfma_f32_16x16x32_bf16(P##a3, P##b1, acc[3][1], 0, 0, 0); \
    acc[3][2] = __builtin_amdgcn_mfma_f32_16x16x32_bf16(P##a3, P##b2, acc[3][2], 0, 0, 0); \
    acc[3][3] = __builtin_amdgcn_mfma_f32_16x16x32_bf16(P##a3, P##b3, acc[3][3], 0, 0, 0);

// scheduling groups: 8 VMEM-reads (0x020), 16 MFMA (0x008)
#define SGB_LD __builtin_amdgcn_sched_group_barrier(0x020, 8, 0);
#define SGB_MM __builtin_amdgcn_sched_group_barrier(0x008, 16, 0);

__global__ __launch_bounds__(256) void k_gemm(
    const unsigned short* __restrict__ xyT, const unsigned short* __restrict__ wtT,
    const unsigned short* __restrict__ bsl, const int* __restrict__ cnt,
    unsigned short* __restrict__ out, float* __restrict__ pstats)
{
    const int tid = threadIdx.x;
    const int wave = tid >> 6, lane = tid & 63;
    const int quad = lane >> 4, l16 = lane & 15;
    const int m0 = blockIdx.x * 128;
    const int rbase = (wave >> 1) * 64;
    const int col0 = (wave & 1) * 64;

    const int gmt = blockIdx.x * 8 + (wave >> 1) * 4;
    const unsigned short* pA0 = xyT + (size_t)(gmt + 0) * TILE_U + quad * 128 + l16 * 8;
    const unsigned short* pA1 = xyT + (size_t)(gmt + 1) * TILE_U + quad * 128 + l16 * 8;
    const unsigned short* pA2 = xyT + (size_t)(gmt + 2) * TILE_U + quad * 128 + l16 * 8;
    const unsigned short* pA3 = xyT + (size_t)(gmt + 3) * TILE_U + quad * 128 + l16 * 8;
    const int jt0 = (wave & 1) * 4;
    const unsigned short* pB0 = wtT + (size_t)(jt0 + 0) * TILE_U + quad * 128 + l16 * 8;
    const unsigned short* pB1 = wtT + (size_t)(jt0 + 1) * TILE_U + quad * 128 + l16 * 8;
    const unsigned short* pB2 = wtT + (size_t)(jt0 + 2) * TILE_U + quad * 128 + l16 * 8;
    const unsigned short* pB3 = wtT + (size_t)(jt0 + 3) * TILE_U + quad * 128 + l16 * 8;

    f4 acc[4][4];
#pragma unroll
    for (int i = 0; i < 4; ++i)
#pragma unroll
        for (int j = 0; j < 4; ++j)
#pragma unroll
            for (int r = 0; r < 4; ++r) acc[i][j][r] = 0.f;

    short8 xa0, xa1, xa2, xa3, xb0, xb1, xb2, xb3;
    short8 ya0, ya1, ya2, ya3, yb0, yb1, yb2, yb3;

    LDSET(x, 0)  SGB_LD
    LDSET(y, 1)  SGB_LD  MMSET(x) SGB_MM
    LDSET(x, 2)  SGB_LD  MMSET(y) SGB_MM
    LDSET(y, 3)  SGB_LD  MMSET(x) SGB_MM
    LDSET(x, 4)  SGB_LD  MMSET(y) SGB_MM
    LDSET(y, 5)  SGB_LD  MMSET(x) SGB_MM
    LDSET(x, 6)  SGB_LD  MMSET(y) SGB_MM
    LDSET(y, 7)  SGB_LD  MMSET(x) SGB_MM
    LDSET(x, 8)  SGB_LD  MMSET(y) SGB_MM
    LDSET(y, 9)  SGB_LD  MMSET(x) SGB_MM
    LDSET(x, 10) SGB_LD  MMSET(y) SGB_MM
    LDSET(y, 11) SGB_LD  MMSET(x) SGB_MM
    LDSET(x, 12) SGB_LD  MMSET(y) SGB_MM
    LDSET(y, 13) SGB_LD  MMSET(x) SGB_MM
    LDSET(x, 14) SGB_LD  MMSET(y) SGB_MM
    LDSET(y, 15) SGB_LD  MMSET(x) SGB_MM
    LDSET(x, 16) SGB_LD  MMSET(y) SGB_MM
    LDSET(y, 17) SGB_LD  MMSET(x) SGB_MM
    LDSET(x, 18) SGB_LD  MMSET(y) SGB_MM
    LDSET(y, 19) SGB_LD  MMSET(x) SGB_MM
    MMSET(y) SGB_MM

    // epilogue: o = (acc + bias)/deg ; store bf16 ; block-local BN stats
    float s_sum[4] = {0, 0, 0, 0}, s_ssq[4] = {0, 0, 0, 0};
#pragma unroll
    for (int i = 0; i < 4; ++i) {
#pragma unroll
        for (int r = 0; r < 4; ++r) {
            const int row = m0 + rbase + i * 16 + quad * 4 + r;
            const int rc = row < N_ENTS ? row : N_ENTS - 1;
            const float rdeg = 1.0f / fmaxf((float)cnt[rc], 1.0f);
            const bool valid = row < N_ENTS;
#pragma unroll
            for (int j = 0; j < 4; ++j) {
                const int f = col0 + j * 16 + l16;
                const float o = (acc[i][j][r] + bf2f(bsl[f])) * rdeg;
                if (valid) {
                    out[(size_t)row * DIM + f] = f2bf(o);
                    s_sum[j] += o;
                    s_ssq[j] += o * o;
                }
            }
        }
    }
    __shared__ float ssum[4][64], sssq[4][64];
#pragma unroll
    for (int j = 0; j < 4; ++j) {
        float s = s_sum[j], q2 = s_ssq[j];
        s += __shfl_xor(s, 16, 64); s += __shfl_xor(s, 32, 64);
        q2 += __shfl_xor(q2, 16, 64); q2 += __shfl_xor(q2, 32, 64);
        if (quad == 0) {
            ssum[wave][j * 16 + l16] = s;
            sssq[wave][j * 16 + l16] = q2;
        }
    }
    __syncthreads();
    {
        const int f = tid & 127;
        const int g = f >> 6;
        const int fl = f & 63;
        const float v = (tid < 128) ? (ssum[g][fl] + ssum[g + 2][fl])
                                    : (sssq[g][fl] + sssq[g + 2][fl]);
        pstats[(size_t)blockIdx.x * 256 + tid] = v;
    }
}

// ---------------- reduce per-block stats -> st[256] ----------------
__global__ __launch_bounds__(256) void k_stats(const float* __restrict__ pstats,
                                               float* __restrict__ st) {
    const int o = threadIdx.x;
    const int b0 = blockIdx.x * 49;
    float s = 0.f;
    for (int b = b0; b < b0 + 49 && b < NBLK; ++b)
        s += pstats[(size_t)b * 256 + o];
    atomicAdd(&st[o], s);
}

// ---------------- BN apply + ReLU: outb(bf16) -> xrow (+ xyT x-cols if l==0) ----------------
__global__ __launch_bounds__(256) void k_bn(
    const unsigned short* __restrict__ out, const float* __restrict__ st,
    const unsigned short* __restrict__ gamma, const unsigned short* __restrict__ beta,
    unsigned short* __restrict__ xrow, unsigned short* __restrict__ xyT, int writeTiled)
{
    const int tile = blockIdx.x;                 // grid exact: 6250
    const int kc = threadIdx.x >> 4, r = threadIdx.x & 15;
    const int n = tile * 16 + r;
    const size_t e0 = (size_t)n * DIM + kc * 8;
    const uint4 u = *(const uint4*)(out + e0);
    const uint uu[4] = {u.x, u.y, u.z, u.w};
    const float inv_n = 1.0f / (float)N_ENTS;
    uint w[4];
#pragma unroll
    for (int p = 0; p < 4; ++p) {
        const int f0 = kc * 8 + p * 2;
        float v0 = bflo(uu[p]), v1 = bfhi(uu[p]);
        const float mu0 = st[f0] * inv_n, mu1 = st[f0 + 1] * inv_n;
        const float var0 = st[DIM + f0] * inv_n - mu0 * mu0;
        const float var1 = st[DIM + f0 + 1] * inv_n - mu1 * mu1;
        const float g0 = bf2f(gamma[f0]) * rsqrtf(var0 + BN_EPS);
        const float g1 = bf2f(gamma[f0 + 1]) * rsqrtf(var1 + BN_EPS);
        v0 = fmaxf((v0 - mu0) * g0 + bf2f(beta[f0]), 0.f);
        v1 = fmaxf((v1 - mu1) * g1 + bf2f(beta[f0 + 1]), 0.f);
        w[p] = pack2(v0, v1);
    }
    uint4 wv = {w[0], w[1], w[2], w[3]};
    *(uint4*)(xrow + e0) = wv;
    if (writeTiled)
        *(uint4*)(xyT + (size_t)tile * TILE_U + kc * 128 + r * 8) = wv;
}

// ---------------- scoring ----------------
__global__ __launch_bounds__(256) void k_hr(
    const int* __restrict__ head, const int* __restrict__ rel,
    const unsigned short* __restrict__ xrow, const unsigned short* __restrict__ rtab,
    float* __restrict__ hr)
{
    const int wave = threadIdx.x >> 6, lane = threadIdx.x & 63;
    const int i = blockIdx.x * 4 + wave;
    const int h = head[i], r = rel[i];
    const uint hv = ((const uint*)xrow)[(size_t)h * 64 + lane];
    const uint rv = ((const uint*)rtab)[(size_t)r * 64 + lane];
    float2 o;
    o.x = bflo(hv) + bflo(rv);
    o.y = bfhi(hv) + bfhi(rv);
    *(float2*)(hr + (size_t)i * DIM + 2 * lane) = o;
}

__global__ __launch_bounds__(256) void k_score(
    const int* __restrict__ tail, const int* __restrict__ negi,
    const float* __restrict__ hr, const unsigned short* __restrict__ xrow,
    void* __restrict__ outp, const int* __restrict__ flag)
{
    const int wave = threadIdx.x >> 6, lane = threadIdx.x & 63;
    const int w = blockIdx.x * 4 + wave;
    int i, t, o;
    if (w < BATCH) { i = w; t = tail[w]; o = w; }
    else { const int w2 = w - BATCH; i = w2 >> 6; t = negi[w2]; o = w; }
    const float2 h = *(const float2*)(hr + (size_t)i * DIM + 2 * lane);
    const uint tv = ((const uint*)xrow)[(size_t)t * 64 + lane];
    const float d0 = h.x - bflo(tv), d1 = h.y - bfhi(tv);
    float s = d0 * d0 + d1 * d1;
#pragma unroll
    for (int m = 32; m >= 1; m >>= 1) s += __shfl_xor(s, m, 64);
    if (lane == 0) {
        const float v = -sqrtf(s);
        if (flag[0]) ((unsigned short*)outp)[o] = f2bf(v);
        else         ((float*)outp)[o] = v;
    }
}

extern "C" void kernel_launch(void* const* d_in, const int* in_sizes, int n_in,
                              void* d_out, int out_size, void* d_ws, size_t ws_size,
                              hipStream_t stream)
{
    const int* head = (const int*)d_in[0];
    const int* rel  = (const int*)d_in[1];
    const int* tail = (const int*)d_in[2];
    const int* negi = (const int*)d_in[3];
    const int* eidx = (const int*)d_in[4];
    const int* etyp = (const int*)d_in[5];
    const void* ent_tab = d_in[6];
    const void* rtab_in = d_in[7];
    const void* bases_in = d_in[8];
    const void* coeffs_in = d_in[9];
    const void* wsl_in = d_in[10];
    const void* bsl_in = d_in[11];
    const void* gamma_in = d_in[12];
    const void* beta_in = d_in[13];

    char* ws = (char*)d_ws;
    size_t off = 0;
    auto alloc = [&](size_t bytes) -> char* {
        char* p = ws + off;
        off += (bytes + 511) & ~(size_t)511;
        return p;
    };
    int* flag            = (int*)alloc(4);
    int* cnt             = (int*)alloc((size_t)N_ENTS * 4);
    int* starts          = (int*)alloc((size_t)N_ENTS * 4);
    int* bsum            = (int*)alloc(391 * 4);
    int* cur             = (int*)alloc((size_t)N_ENTS * 4);
    uint* ebuf           = (uint*)alloc((size_t)NEDGE * 4);
    unsigned short* xyT  = (unsigned short*)alloc((size_t)NTILES * TILE_U * 2); // 128.1 MB tiled
    unsigned short* xrow = (unsigned short*)alloc((size_t)N_ENTS * DIM * 2);    // 25.6 MB row-major
    unsigned short* outb = (unsigned short*)alloc((size_t)M_PAD * DIM * 2);     // 25.6 MB bf16
    unsigned short* par  = (unsigned short*)alloc((size_t)P_TOTAL * 2);
    unsigned short* WtT  = (unsigned short*)alloc((size_t)2 * 81920 * 2);
    float* pstats        = (float*)alloc((size_t)NBLK * 256 * 4);
    float* hr            = (float*)alloc((size_t)BATCH * DIM * 4);
    float* stats         = (float*)alloc(2 * 2 * DIM * 4);
    (void)ws_size; (void)in_sizes; (void)n_in; (void)out_size;

    const int* esrc = eidx;
    const int* edst = eidx + NEDGE;

    k_detect<<<1, 256, 0, stream>>>((const unsigned int*)ent_tab, flag);

    k_conv_x<<<N_ENTS / 16, 256, 0, stream>>>(ent_tab, xrow, xyT, flag);
    k_conv_params<<<(P_TOTAL + 255) / 256, 256, 0, stream>>>(
        rtab_in, bases_in, coeffs_in, wsl_in, bsl_in, gamma_in, beta_in, par, flag);
    k_transw2<<<80, 256, 0, stream>>>(par, WtT);

    hipMemsetAsync(cnt, 0, (size_t)N_ENTS * 4, stream);
    hipMemsetAsync(cur, 0, (size_t)N_ENTS * 4, stream);
    hipMemsetAsync(stats, 0, 2 * 2 * DIM * 4, stream);

    k_count<<<NEDGE / 256, 256, 0, stream>>>(edst, cnt);
    k_bsum<<<391, 256, 0, stream>>>(cnt, bsum);
    k_scan1<<<1, 512, 0, stream>>>(bsum);
    k_starts<<<391, 256, 0, stream>>>(cnt, bsum, starts);
    k_fill<<<NEDGE / 256, 256, 0, stream>>>(esrc, edst, etyp, starts, cur, ebuf);

    for (int l = 0; l < 2; ++l) {
        const unsigned short* bl = par + P_BSL   + l * DIM;
        const unsigned short* cf = par + P_COEFF + l * N_RELS * NB;
        const unsigned short* gm = par + P_GAMMA + l * DIM;
        const unsigned short* bt = par + P_BETA  + l * DIM;
        const unsigned short* wt = WtT + (size_t)l * 81920;
        float* st = stats + l * 2 * DIM;

        k_agg<<<N_ENTS / 4, 256, 0, stream>>>(ebuf, starts, cnt, cf, xrow, xyT);
        k_gemm<<<NBLK, 256, 0, stream>>>(xyT, wt, bl, cnt, outb, pstats);
        k_stats<<<16, 256, 0, stream>>>(pstats, st);
        k_bn<<<N_ENTS / 16, 256, 0, stream>>>(outb, st, gm, bt, xrow, xyT, l == 0 ? 1 : 0);
    }

    k_hr<<<BATCH / 4, 256, 0, stream>>>(head, rel, xrow, par + P_REL, hr);
    k_score<<<(BATCH + BATCH * NNEG) / 4, 256, 0, stream>>>(tail, negi, hr, xrow, d_out, flag);
}

// Round 11
// 467.900 us; speedup vs baseline: 1.2306x; 1.0558x over previous
//
#include <hip/hip_runtime.h>
#include <stdint.h>

// Problem constants
#define N_ENTS  100000
#define M_PAD   100096          // 782 * 128
#define NTILES  6256            // M_PAD/16
#define N_RELS  16
#define DIM     128
#define NB      4
#define KTOT    640             // 128 (self) + 4*128 (bases)
#define TILE_U  10240           // ushorts per m-tile: 80*16*8
#define NEDGE   640000
#define BATCH   1024
#define NNEG    64
#define BN_EPS  1e-5f
#define NBLK    782             // M_PAD/128
#define BCAP    64              // bucket capacity per node

// converted-parameter buffer layout (ushort offsets)
#define P_REL    0        // [16][128]
#define P_BASES  2048     // [2][4][128][128]
#define P_COEFF  133120   // [2][16][4]
#define P_WSL    133248   // [2][128][128]
#define P_BSL    166016   // [2][128]
#define P_GAMMA  166272   // [2][128]
#define P_BETA   166528   // [2][128]
#define P_TOTAL  166784

typedef unsigned int uint;
typedef short short8 __attribute__((ext_vector_type(8)));
typedef float f4 __attribute__((ext_vector_type(4)));

__device__ __forceinline__ float bf2f(unsigned short u) {
    return __uint_as_float(((unsigned int)u) << 16);
}
__device__ __forceinline__ float bflo(unsigned int u) { return __uint_as_float(u << 16); }
__device__ __forceinline__ float bfhi(unsigned int u) { return __uint_as_float(u & 0xffff0000u); }
__device__ __forceinline__ unsigned short f2bf(float f) {
    unsigned int x = __float_as_uint(f);
    x += 0x7fffu + ((x >> 16) & 1u);
    return (unsigned short)(x >> 16);
}
__device__ __forceinline__ unsigned int pack2(float a, float b) {
    return (unsigned int)f2bf(a) | ((unsigned int)f2bf(b) << 16);
}

// ---------------- dtype detection (fp32 vs bf16 storage) ----------------
__device__ __forceinline__ int bf16_like(unsigned int h) {
    unsigned int m = h & 0x7FFFu;
    return (m == 0u) || (m >= 0x2D00u && m < 0x4400u);
}
__global__ __launch_bounds__(256) void k_detect(const unsigned int* __restrict__ ent,
                                                int* __restrict__ flag) {
    __shared__ int cnt[256];
    unsigned int u = ent[threadIdx.x];
    cnt[threadIdx.x] = bf16_like(u & 0xFFFFu) & bf16_like(u >> 16);
    __syncthreads();
    for (int s = 128; s > 0; s >>= 1) {
        if (threadIdx.x < s) cnt[threadIdx.x] += cnt[threadIdx.x + s];
        __syncthreads();
    }
    if (threadIdx.x == 0) flag[0] = (cnt[0] >= 140) ? 1 : 0;
}

// ---------------- converts ----------------
__device__ __forceinline__ unsigned short cvt1(const void* src, int i, int isbf) {
    return isbf ? ((const unsigned short*)src)[i] : f2bf(((const float*)src)[i]);
}
__global__ __launch_bounds__(256) void k_conv_params(
    const void* __restrict__ rtab, const void* __restrict__ bases,
    const void* __restrict__ coeffs, const void* __restrict__ wsl,
    const void* __restrict__ bsl, const void* __restrict__ gamma,
    const void* __restrict__ beta,
    unsigned short* __restrict__ par, const int* __restrict__ flag)
{
    const int i = blockIdx.x * 256 + threadIdx.x;
    if (i >= P_TOTAL) return;
    const int isbf = flag[0];
    unsigned short v;
    if      (i < P_BASES)  v = cvt1(rtab,   i - P_REL,    isbf);
    else if (i < P_COEFF)  v = cvt1(bases,  i - P_BASES,  isbf);
    else if (i < P_WSL)    v = cvt1(coeffs, i - P_COEFF,  isbf);
    else if (i < P_BSL)    v = cvt1(wsl,    i - P_WSL,    isbf);
    else if (i < P_GAMMA)  v = cvt1(bsl,    i - P_BSL,    isbf);
    else if (i < P_BETA)   v = cvt1(gamma,  i - P_GAMMA,  isbf);
    else                   v = cvt1(beta,   i - P_BETA,   isbf);
    par[i] = v;
}

// entity -> xrow (row-major) + xyT tiled x-cols. block = one m-tile (16 rows x 16 kc)
__global__ __launch_bounds__(256) void k_conv_x(const void* __restrict__ src,
                                                unsigned short* __restrict__ xrow,
                                                unsigned short* __restrict__ xyT,
                                                const int* __restrict__ flag) {
    const int tile = blockIdx.x;                 // grid exact: 6250
    const int kc = threadIdx.x >> 4, r = threadIdx.x & 15;
    const int n = tile * 16 + r;                 // always < N_ENTS
    const size_t e0 = (size_t)n * DIM + kc * 8;
    uint4 w;
    if (flag[0]) {
        w = *(const uint4*)((const unsigned short*)src + e0);
    } else {
        const float4 f0 = *(const float4*)((const float*)src + e0);
        const float4 f1 = *(const float4*)((const float*)src + e0 + 4);
        w.x = pack2(f0.x, f0.y); w.y = pack2(f0.z, f0.w);
        w.z = pack2(f1.x, f1.y); w.w = pack2(f1.z, f1.w);
    }
    *(uint4*)(xrow + e0) = w;
    *(uint4*)(xyT + (size_t)tile * TILE_U + kc * 128 + r * 8) = w;
}

// ---------------- one-kernel bucket CSR: cnt + bucket[n][64] ----------------
__global__ __launch_bounds__(256) void k_fillB(const int* __restrict__ src, const int* __restrict__ dst,
                                               const int* __restrict__ et, int* __restrict__ cnt,
                                               uint* __restrict__ bucket) {
    const int e = blockIdx.x * 256 + threadIdx.x;   // grid exact: NEDGE/256
    const int d = dst[e];
    const int p = atomicAdd(&cnt[d], 1);
    if (p < BCAP) bucket[(size_t)d * BCAP + p] = (uint)src[e] | ((uint)et[e] << 20);
}

// ---------------- edge aggregation: 8-stream gather from buckets ----------------
__global__ __launch_bounds__(256) void k_agg(
    const uint* __restrict__ bucket, const int* __restrict__ cnt,
    const unsigned short* __restrict__ coeffs, const unsigned short* __restrict__ xrow,
    unsigned short* __restrict__ xyT)
{
    __shared__ uint2 scf[16];
    if (threadIdx.x < 16) scf[threadIdx.x] = *(const uint2*)(coeffs + threadIdx.x * 4);
    __syncthreads();
    const int wave = threadIdx.x >> 6, lane = threadIdx.x & 63;
    const int n = blockIdx.x * 4 + wave;   // grid exact: N_ENTS/4
    int cn = cnt[n]; if (cn > BCAP) cn = BCAP;
    const uint* __restrict__ bk = bucket + (size_t)n * BCAP;
    const int q = (cn + 7) >> 3;
    float lo[4][NB] = {}, hi[4][NB] = {};
    const uint* __restrict__ x32 = (const uint*)xrow;
    for (int i = 0; i < q; ++i) {
        uint rec[8];
        int valid[8];
#pragma unroll
        for (int s = 0; s < 8; ++s) {
            const int p = s * q + i;
            valid[s] = p < cn;
            rec[s] = valid[s] ? bk[p] : 0u;   // rec=0 -> src 0 (in-range), coeff zeroed below
        }
        uint xw[8];
#pragma unroll
        for (int s = 0; s < 8; ++s)
            xw[s] = x32[(size_t)(rec[s] & 0xFFFFFu) * 64 + lane];
#pragma unroll
        for (int s = 0; s < 8; ++s) {
            uint2 cc = scf[rec[s] >> 20];
            if (!valid[s]) { cc.x = 0; cc.y = 0; }
            const float cb[NB] = {bflo(cc.x), bfhi(cc.x), bflo(cc.y), bfhi(cc.y)};
            const float xl = bflo(xw[s]), xh = bfhi(xw[s]);
#pragma unroll
            for (int b = 0; b < NB; ++b) {
                lo[s & 3][b] = fmaf(cb[b], xl, lo[s & 3][b]);
                hi[s & 3][b] = fmaf(cb[b], xh, hi[s & 3][b]);
            }
        }
    }
    const size_t tb = (size_t)(n >> 4) * TILE_U + (n & 15) * 8;
#pragma unroll
    for (int b = 0; b < NB; ++b) {
        const float l = (lo[0][b] + lo[1][b]) + (lo[2][b] + lo[3][b]);
        const float h = (hi[0][b] + hi[1][b]) + (hi[2][b] + hi[3][b]);
        *(uint*)(xyT + tb + (size_t)(16 + b * 16 + (lane >> 2)) * 128 + (lane & 3) * 2) = pack2(l, h);
    }
}

// ---------------- build WtT tiled for BOTH layers: [l][jt 8][kc 80][r 16][8] ----------------
__global__ __launch_bounds__(256) void k_transw2(const unsigned short* __restrict__ par,
                                                 unsigned short* __restrict__ WtT) {
    const int i = blockIdx.x * 256 + threadIdx.x;   // grid exact: 20480/256 = 80
    const int l = i / 10240;
    const int rem = i - l * 10240;
    const int jt2 = rem / 1280;
    const int rem2 = rem - jt2 * 1280;
    const int kc = rem2 >> 4, r = rem2 & 15;
    const int n = jt2 * 16 + r;
    unsigned short v[8];
#pragma unroll
    for (int e = 0; e < 8; ++e) {
        const int k = kc * 8 + e;
        v[e] = (k < DIM)
            ? par[P_WSL + l * DIM * DIM + k * DIM + n]
            : par[P_BASES + l * NB * DIM * DIM + (k - DIM) * DIM + n];
    }
    *(uint4*)(WtT + (size_t)l * 81920 + (size_t)jt2 * TILE_U + (size_t)kc * 128 + r * 8) = *(uint4*)v;
}

// ---------------- tiled MFMA GEMM, named-register double buffer + sched groups ----------------
#define LDSET(P, s) \
    P##a0 = *(const short8*)(pA0 + (s) * 512); \
    P##a1 = *(const short8*)(pA1 + (s) * 512); \
    P##a2 = *(const short8*)(pA2 + (s) * 512); \
    P##a3 = *(const short8*)(pA3 + (s) * 512); \
    P##b0 = *(const short8*)(pB0 + (s) * 512); \
    P##b1 = *(const short8*)(pB1 + (s) * 512); \
    P##b2 = *(const short8*)(pB2 + (s) * 512); \
    P##b3 = *(const short8*)(pB3 + (s) * 512);

#define MMSET(P) \
    acc[0][0] = __builtin_amdgcn_mfma_f32_16x16x32_bf16(P##a0, P##b0, acc[0][0], 0, 0, 0); \
    acc[0][1] = __builtin_amdgcn_mfma_f32_16x16x32_bf16(P##a0, P##b1, acc[0][1], 0, 0, 0); \
    acc[0][2] = __builtin_amdgcn_mfma_f32_16x16x32_bf16(P##a0, P##b2, acc[0][2], 0, 0, 0); \
    acc[0][3] = __builtin_amdgcn_mfma_f32_16x16x32_bf16(P##a0, P##b3, acc[0][3], 0, 0, 0); \
    acc[1][0] = __builtin_amdgcn_mfma_f32_16x16x32_bf16(P##a1, P##b0, acc[1][0], 0, 0, 0); \
    acc[1][1] = __builtin_amdgcn_mfma_f32_16x16x32_bf16(P##a1, P##b1, acc[1][1], 0, 0, 0); \
    acc[1][2] = __builtin_amdgcn_mfma_f32_16x16x32_bf16(P##a1, P##b2, acc[1][2], 0, 0, 0); \
    acc[1][3] = __builtin_amdgcn_mfma_f32_16x16x32_bf16(P##a1, P##b3, acc[1][3], 0, 0, 0); \
    acc[2][0] = __builtin_amdgcn_mfma_f32_16x16x32_bf16(P##a2, P##b0, acc[2][0], 0, 0, 0); \
    acc[2][1] = __builtin_amdgcn_mfma_f32_16x16x32_bf16(P##a2, P##b1, acc[2][1], 0, 0, 0); \
    acc[2][2] = __builtin_amdgcn_mfma_f32_16x16x32_bf16(P##a2, P##b2, acc[2][2], 0, 0, 0); \
    acc[2][3] = __builtin_amdgcn_mfma_f32_16x16x32_bf16(P##a2, P##b3, acc[2][3], 0, 0, 0); \
    acc[3][0] = __builtin_amdgcn_mfma_f32_16x16x32_bf16(P##a3, P##b0, acc[3][0], 0, 0, 0); \
    acc[3][1] = __builtin_amdgcn_mfma_f32_16x16x32_bf16(P##a3, P##b1, acc[3][1], 0, 0, 0); \
    acc[3][2] = __builtin_amdgcn_mfma_f32_16x16x32_bf16(P##a3, P##b2, acc[3][2], 0, 0, 0); \
    acc[3][3] = __builtin_amdgcn_mfma_f32_16x16x32_bf16(P##a3, P##b3, acc[3][3], 0, 0, 0);

// scheduling groups: 8 VMEM-reads (0x020), 16 MFMA (0x008)
#define SGB_LD __builtin_amdgcn_sched_group_barrier(0x020, 8, 0);
#define SGB_MM __builtin_amdgcn_sched_group_barrier(0x008, 16, 0);

__global__ __launch_bounds__(256) void k_gemm(
    const unsigned short* __restrict__ xyT, const unsigned short* __restrict__ wtT,
    const unsigned short* __restrict__ bsl, const int* __restrict__ cnt,
    unsigned short* __restrict__ out, float* __restrict__ pstats)
{
    const int tid = threadIdx.x;
    const int wave = tid >> 6, lane = tid & 63;
    const int quad = lane >> 4, l16 = lane & 15;
    const int m0 = blockIdx.x * 128;
    const int rbase = (wave >> 1) * 64;
    const int col0 = (wave & 1) * 64;

    const int gmt = blockIdx.x * 8 + (wave >> 1) * 4;
    const unsigned short* pA0 = xyT + (size_t)(gmt + 0) * TILE_U + quad * 128 + l16 * 8;
    const unsigned short* pA1 = xyT + (size_t)(gmt + 1) * TILE_U + quad * 128 + l16 * 8;
    const unsigned short* pA2 = xyT + (size_t)(gmt + 2) * TILE_U + quad * 128 + l16 * 8;
    const unsigned short* pA3 = xyT + (size_t)(gmt + 3) * TILE_U + quad * 128 + l16 * 8;
    const int jt0 = (wave & 1) * 4;
    const unsigned short* pB0 = wtT + (size_t)(jt0 + 0) * TILE_U + quad * 128 + l16 * 8;
    const unsigned short* pB1 = wtT + (size_t)(jt0 + 1) * TILE_U + quad * 128 + l16 * 8;
    const unsigned short* pB2 = wtT + (size_t)(jt0 + 2) * TILE_U + quad * 128 + l16 * 8;
    const unsigned short* pB3 = wtT + (size_t)(jt0 + 3) * TILE_U + quad * 128 + l16 * 8;

    f4 acc[4][4];
#pragma unroll
    for (int i = 0; i < 4; ++i)
#pragma unroll
        for (int j = 0; j < 4; ++j)
#pragma unroll
            for (int r = 0; r < 4; ++r) acc[i][j][r] = 0.f;

    short8 xa0, xa1, xa2, xa3, xb0, xb1, xb2, xb3;
    short8 ya0, ya1, ya2, ya3, yb0, yb1, yb2, yb3;

    LDSET(x, 0)  SGB_LD
    LDSET(y, 1)  SGB_LD  MMSET(x) SGB_MM
    LDSET(x, 2)  SGB_LD  MMSET(y) SGB_MM
    LDSET(y, 3)  SGB_LD  MMSET(x) SGB_MM
    LDSET(x, 4)  SGB_LD  MMSET(y) SGB_MM
    LDSET(y, 5)  SGB_LD  MMSET(x) SGB_MM
    LDSET(x, 6)  SGB_LD  MMSET(y) SGB_MM
    LDSET(y, 7)  SGB_LD  MMSET(x) SGB_MM
    LDSET(x, 8)  SGB_LD  MMSET(y) SGB_MM
    LDSET(y, 9)  SGB_LD  MMSET(x) SGB_MM
    LDSET(x, 10) SGB_LD  MMSET(y) SGB_MM
    LDSET(y, 11) SGB_LD  MMSET(x) SGB_MM
    LDSET(x, 12) SGB_LD  MMSET(y) SGB_MM
    LDSET(y, 13) SGB_LD  MMSET(x) SGB_MM
    LDSET(x, 14) SGB_LD  MMSET(y) SGB_MM
    LDSET(y, 15) SGB_LD  MMSET(x) SGB_MM
    LDSET(x, 16) SGB_LD  MMSET(y) SGB_MM
    LDSET(y, 17) SGB_LD  MMSET(x) SGB_MM
    LDSET(x, 18) SGB_LD  MMSET(y) SGB_MM
    LDSET(y, 19) SGB_LD  MMSET(x) SGB_MM
    MMSET(y) SGB_MM

    // epilogue: o = (acc + bias)/deg ; store bf16 ; block-local BN stats
    float s_sum[4] = {0, 0, 0, 0}, s_ssq[4] = {0, 0, 0, 0};
#pragma unroll
    for (int i = 0; i < 4; ++i) {
#pragma unroll
        for (int r = 0; r < 4; ++r) {
            const int row = m0 + rbase + i * 16 + quad * 4 + r;
            const int rc = row < N_ENTS ? row : N_ENTS - 1;
            const float rdeg = 1.0f / fmaxf((float)cnt[rc], 1.0f);
            const bool valid = row < N_ENTS;
#pragma unroll
            for (int j = 0; j < 4; ++j) {
                const int f = col0 + j * 16 + l16;
                const float o = (acc[i][j][r] + bf2f(bsl[f])) * rdeg;
                if (valid) {
                    out[(size_t)row * DIM + f] = f2bf(o);
                    s_sum[j] += o;
                    s_ssq[j] += o * o;
                }
            }
        }
    }
    __shared__ float ssum[4][64], sssq[4][64];
#pragma unroll
    for (int j = 0; j < 4; ++j) {
        float s = s_sum[j], q2 = s_ssq[j];
        s += __shfl_xor(s, 16, 64); s += __shfl_xor(s, 32, 64);
        q2 += __shfl_xor(q2, 16, 64); q2 += __shfl_xor(q2, 32, 64);
        if (quad == 0) {
            ssum[wave][j * 16 + l16] = s;
            sssq[wave][j * 16 + l16] = q2;
        }
    }
    __syncthreads();
    {
        const int f = tid & 127;
        const int g = f >> 6;
        const int fl = f & 63;
        const float v = (tid < 128) ? (ssum[g][fl] + ssum[g + 2][fl])
                                    : (sssq[g][fl] + sssq[g + 2][fl]);
        pstats[(size_t)blockIdx.x * 256 + tid] = v;
    }
}

// ---------------- reduce per-block stats -> st[256] ----------------
__global__ __launch_bounds__(256) void k_stats(const float* __restrict__ pstats,
                                               float* __restrict__ st) {
    const int o = threadIdx.x;
    const int b0 = blockIdx.x * 49;
    float s = 0.f;
    for (int b = b0; b < b0 + 49 && b < NBLK; ++b)
        s += pstats[(size_t)b * 256 + o];
    atomicAdd(&st[o], s);
}

// ---------------- BN apply + ReLU: outb(bf16) -> xrow (+ xyT x-cols if l==0) ----------------
__global__ __launch_bounds__(256) void k_bn(
    const unsigned short* __restrict__ out, const float* __restrict__ st,
    const unsigned short* __restrict__ gamma, const unsigned short* __restrict__ beta,
    unsigned short* __restrict__ xrow, unsigned short* __restrict__ xyT, int writeTiled)
{
    const int tile = blockIdx.x;                 // grid exact: 6250
    const int kc = threadIdx.x >> 4, r = threadIdx.x & 15;
    const int n = tile * 16 + r;
    const size_t e0 = (size_t)n * DIM + kc * 8;
    const uint4 u = *(const uint4*)(out + e0);
    const uint uu[4] = {u.x, u.y, u.z, u.w};
    const float inv_n = 1.0f / (float)N_ENTS;
    uint w[4];
#pragma unroll
    for (int p = 0; p < 4; ++p) {
        const int f0 = kc * 8 + p * 2;
        float v0 = bflo(uu[p]), v1 = bfhi(uu[p]);
        const float mu0 = st[f0] * inv_n, mu1 = st[f0 + 1] * inv_n;
        const float var0 = st[DIM + f0] * inv_n - mu0 * mu0;
        const float var1 = st[DIM + f0 + 1] * inv_n - mu1 * mu1;
        const float g0 = bf2f(gamma[f0]) * rsqrtf(var0 + BN_EPS);
        const float g1 = bf2f(gamma[f0 + 1]) * rsqrtf(var1 + BN_EPS);
        v0 = fmaxf((v0 - mu0) * g0 + bf2f(beta[f0]), 0.f);
        v1 = fmaxf((v1 - mu1) * g1 + bf2f(beta[f0 + 1]), 0.f);
        w[p] = pack2(v0, v1);
    }
    uint4 wv = {w[0], w[1], w[2], w[3]};
    *(uint4*)(xrow + e0) = wv;
    if (writeTiled)
        *(uint4*)(xyT + (size_t)tile * TILE_U + kc * 128 + r * 8) = wv;
}

// ---------------- fused scoring (hr recomputed inline) ----------------
__global__ __launch_bounds__(256) void k_score(
    const int* __restrict__ head, const int* __restrict__ rel,
    const int* __restrict__ tail, const int* __restrict__ negi,
    const unsigned short* __restrict__ xrow, const unsigned short* __restrict__ rtab,
    void* __restrict__ outp, const int* __restrict__ flag)
{
    const int wave = threadIdx.x >> 6, lane = threadIdx.x & 63;
    const int w = blockIdx.x * 4 + wave;   // grid exact: (BATCH + BATCH*NNEG)/4
    int i, t;
    if (w < BATCH) { i = w; t = tail[w]; }
    else { const int w2 = w - BATCH; i = w2 >> 6; t = negi[w2]; }
    const uint hv = ((const uint*)xrow)[(size_t)head[i] * 64 + lane];
    const uint rv = ((const uint*)rtab)[(size_t)rel[i] * 64 + lane];
    const uint tv = ((const uint*)xrow)[(size_t)t * 64 + lane];
    const float d0 = (bflo(hv) + bflo(rv)) - bflo(tv);
    const float d1 = (bfhi(hv) + bfhi(rv)) - bfhi(tv);
    float s = d0 * d0 + d1 * d1;
#pragma unroll
    for (int m = 32; m >= 1; m >>= 1) s += __shfl_xor(s, m, 64);
    if (lane == 0) {
        const float v = -sqrtf(s);
        if (flag[0]) ((unsigned short*)outp)[w] = f2bf(v);
        else         ((float*)outp)[w] = v;
    }
}

extern "C" void kernel_launch(void* const* d_in, const int* in_sizes, int n_in,
                              void* d_out, int out_size, void* d_ws, size_t ws_size,
                              hipStream_t stream)
{
    const int* head = (const int*)d_in[0];
    const int* rel  = (const int*)d_in[1];
    const int* tail = (const int*)d_in[2];
    const int* negi = (const int*)d_in[3];
    const int* eidx = (const int*)d_in[4];
    const int* etyp = (const int*)d_in[5];
    const void* ent_tab = d_in[6];
    const void* rtab_in = d_in[7];
    const void* bases_in = d_in[8];
    const void* coeffs_in = d_in[9];
    const void* wsl_in = d_in[10];
    const void* bsl_in = d_in[11];
    const void* gamma_in = d_in[12];
    const void* beta_in = d_in[13];

    char* ws = (char*)d_ws;
    size_t off = 0;
    auto alloc = [&](size_t bytes) -> char* {
        char* p = ws + off;
        off += (bytes + 511) & ~(size_t)511;
        return p;
    };
    int* flag            = (int*)alloc(4);
    int* cnt             = (int*)alloc((size_t)N_ENTS * 4);
    uint* bucket         = (uint*)alloc((size_t)N_ENTS * BCAP * 4);             // 25.6 MB
    unsigned short* xyT  = (unsigned short*)alloc((size_t)NTILES * TILE_U * 2); // 128.1 MB tiled
    unsigned short* xrow = (unsigned short*)alloc((size_t)N_ENTS * DIM * 2);    // 25.6 MB row-major
    unsigned short* outb = (unsigned short*)alloc((size_t)M_PAD * DIM * 2);     // 25.6 MB bf16
    unsigned short* par  = (unsigned short*)alloc((size_t)P_TOTAL * 2);
    unsigned short* WtT  = (unsigned short*)alloc((size_t)2 * 81920 * 2);
    float* pstats        = (float*)alloc((size_t)NBLK * 256 * 4);
    float* stats         = (float*)alloc(2 * 2 * DIM * 4);
    (void)ws_size; (void)in_sizes; (void)n_in; (void)out_size;

    const int* esrc = eidx;
    const int* edst = eidx + NEDGE;

    k_detect<<<1, 256, 0, stream>>>((const unsigned int*)ent_tab, flag);

    k_conv_x<<<N_ENTS / 16, 256, 0, stream>>>(ent_tab, xrow, xyT, flag);
    k_conv_params<<<(P_TOTAL + 255) / 256, 256, 0, stream>>>(
        rtab_in, bases_in, coeffs_in, wsl_in, bsl_in, gamma_in, beta_in, par, flag);
    k_transw2<<<80, 256, 0, stream>>>(par, WtT);

    hipMemsetAsync(cnt, 0, (size_t)N_ENTS * 4, stream);
    hipMemsetAsync(stats, 0, 2 * 2 * DIM * 4, stream);

    k_fillB<<<NEDGE / 256, 256, 0, stream>>>(esrc, edst, etyp, cnt, bucket);

    for (int l = 0; l < 2; ++l) {
        const unsigned short* bl = par + P_BSL   + l * DIM;
        const unsigned short* cf = par + P_COEFF + l * N_RELS * NB;
        const unsigned short* gm = par + P_GAMMA + l * DIM;
        const unsigned short* bt = par + P_BETA  + l * DIM;
        const unsigned short* wt = WtT + (size_t)l * 81920;
        float* st = stats + l * 2 * DIM;

        k_agg<<<N_ENTS / 4, 256, 0, stream>>>(bucket, cnt, cf, xrow, xyT);
        k_gemm<<<NBLK, 256, 0, stream>>>(xyT, wt, bl, cnt, outb, pstats);
        k_stats<<<16, 256, 0, stream>>>(pstats, st);
        k_bn<<<N_ENTS / 16, 256, 0, stream>>>(outb, st, gm, bt, xrow, xyT, l == 0 ? 1 : 0);
    }

    k_score<<<(BATCH + BATCH * NNEG) / 4, 256, 0, stream>>>(
        head, rel, tail, negi, xrow, par + P_REL, d_out, flag);
}

// Round 12
// 461.875 us; speedup vs baseline: 1.2467x; 1.0130x over previous
//
#include <hip/hip_runtime.h>
#include <stdint.h>

// Problem constants
#define N_ENTS  100000
#define M_PAD   100096          // 782 * 128
#define NTILES  6256            // M_PAD/16
#define N_RELS  16
#define DIM     128
#define NB      4
#define KTOT    640             // 128 (self) + 4*128 (bases)
#define TILE_U  10240           // ushorts per m-tile: 80*16*8
#define NEDGE   640000
#define BATCH   1024
#define NNEG    64
#define BN_EPS  1e-5f
#define NBLK    782             // M_PAD/128
#define BCAP    64              // bucket capacity per node
#define SENT    0x01000000u     // sentinel: rel=16 (zero coeff), src=0

// converted-parameter buffer layout (ushort offsets)
#define P_REL    0        // [16][128]
#define P_BASES  2048     // [2][4][128][128]
#define P_COEFF  133120   // [2][16][4]
#define P_WSL    133248   // [2][128][128]
#define P_BSL    166016   // [2][128]
#define P_GAMMA  166272   // [2][128]
#define P_BETA   166528   // [2][128]
#define P_TOTAL  166784

typedef unsigned int uint;
typedef short short8 __attribute__((ext_vector_type(8)));
typedef float f4 __attribute__((ext_vector_type(4)));

__device__ __forceinline__ float bf2f(unsigned short u) {
    return __uint_as_float(((unsigned int)u) << 16);
}
__device__ __forceinline__ float bflo(unsigned int u) { return __uint_as_float(u << 16); }
__device__ __forceinline__ float bfhi(unsigned int u) { return __uint_as_float(u & 0xffff0000u); }
__device__ __forceinline__ unsigned short f2bf(float f) {
    unsigned int x = __float_as_uint(f);
    x += 0x7fffu + ((x >> 16) & 1u);
    return (unsigned short)(x >> 16);
}
__device__ __forceinline__ unsigned int pack2(float a, float b) {
    return (unsigned int)f2bf(a) | ((unsigned int)f2bf(b) << 16);
}

// ---------------- dtype detection (fp32 vs bf16 storage) ----------------
__device__ __forceinline__ int bf16_like(unsigned int h) {
    unsigned int m = h & 0x7FFFu;
    return (m == 0u) || (m >= 0x2D00u && m < 0x4400u);
}
__global__ __launch_bounds__(256) void k_detect(const unsigned int* __restrict__ ent,
                                                int* __restrict__ flag) {
    __shared__ int cnt[256];
    unsigned int u = ent[threadIdx.x];
    cnt[threadIdx.x] = bf16_like(u & 0xFFFFu) & bf16_like(u >> 16);
    __syncthreads();
    for (int s = 128; s > 0; s >>= 1) {
        if (threadIdx.x < s) cnt[threadIdx.x] += cnt[threadIdx.x + s];
        __syncthreads();
    }
    if (threadIdx.x == 0) flag[0] = (cnt[0] >= 140) ? 1 : 0;
}

// ---------------- converts ----------------
__device__ __forceinline__ unsigned short cvt1(const void* src, int i, int isbf) {
    return isbf ? ((const unsigned short*)src)[i] : f2bf(((const float*)src)[i]);
}
__global__ __launch_bounds__(256) void k_conv_params(
    const void* __restrict__ rtab, const void* __restrict__ bases,
    const void* __restrict__ coeffs, const void* __restrict__ wsl,
    const void* __restrict__ bsl, const void* __restrict__ gamma,
    const void* __restrict__ beta,
    unsigned short* __restrict__ par, const int* __restrict__ flag)
{
    const int i = blockIdx.x * 256 + threadIdx.x;
    if (i >= P_TOTAL) return;
    const int isbf = flag[0];
    unsigned short v;
    if      (i < P_BASES)  v = cvt1(rtab,   i - P_REL,    isbf);
    else if (i < P_COEFF)  v = cvt1(bases,  i - P_BASES,  isbf);
    else if (i < P_WSL)    v = cvt1(coeffs, i - P_COEFF,  isbf);
    else if (i < P_BSL)    v = cvt1(wsl,    i - P_WSL,    isbf);
    else if (i < P_GAMMA)  v = cvt1(bsl,    i - P_BSL,    isbf);
    else if (i < P_BETA)   v = cvt1(gamma,  i - P_GAMMA,  isbf);
    else                   v = cvt1(beta,   i - P_BETA,   isbf);
    par[i] = v;
}

// entity -> xrow (row-major) + xyT tiled x-cols. block = one m-tile (16 rows x 16 kc)
__global__ __launch_bounds__(256) void k_conv_x(const void* __restrict__ src,
                                                unsigned short* __restrict__ xrow,
                                                unsigned short* __restrict__ xyT,
                                                const int* __restrict__ flag) {
    const int tile = blockIdx.x;                 // grid exact: 6250
    const int kc = threadIdx.x >> 4, r = threadIdx.x & 15;
    const int n = tile * 16 + r;                 // always < N_ENTS
    const size_t e0 = (size_t)n * DIM + kc * 8;
    uint4 w;
    if (flag[0]) {
        w = *(const uint4*)((const unsigned short*)src + e0);
    } else {
        const float4 f0 = *(const float4*)((const float*)src + e0);
        const float4 f1 = *(const float4*)((const float*)src + e0 + 4);
        w.x = pack2(f0.x, f0.y); w.y = pack2(f0.z, f0.w);
        w.z = pack2(f1.x, f1.y); w.w = pack2(f1.z, f1.w);
    }
    *(uint4*)(xrow + e0) = w;
    *(uint4*)(xyT + (size_t)tile * TILE_U + kc * 128 + r * 8) = w;
}

// ---------------- one-kernel bucket CSR: cnt + bucket[n][64] ----------------
__global__ __launch_bounds__(256) void k_fillB(const int* __restrict__ src, const int* __restrict__ dst,
                                               const int* __restrict__ et, int* __restrict__ cnt,
                                               uint* __restrict__ bucket) {
    const int e = blockIdx.x * 256 + threadIdx.x;   // grid exact: NEDGE/256
    const int d = dst[e];
    const int p = atomicAdd(&cnt[d], 1);
    if (p < BCAP) bucket[(size_t)d * BCAP + p] = (uint)src[e] | ((uint)et[e] << 20);
}
// pad each bucket to a multiple of 8 with sentinel records
__global__ __launch_bounds__(256) void k_pad(const int* __restrict__ cnt,
                                             uint* __restrict__ bucket) {
    const int n = blockIdx.x * 256 + threadIdx.x;
    if (n >= N_ENTS) return;
    int c = cnt[n]; if (c > BCAP) c = BCAP;
    const int e = (c + 7) & ~7;
    uint* b = bucket + (size_t)n * BCAP;
    for (int p = c; p < e; ++p) b[p] = SENT;
}

// ---------------- edge aggregation: unconditional vector loads, sentinel-masked ----------------
__global__ __launch_bounds__(256) void k_agg(
    const uint* __restrict__ bucket, const int* __restrict__ cnt,
    const unsigned short* __restrict__ coeffs, const unsigned short* __restrict__ xrow,
    unsigned short* __restrict__ xyT)
{
    __shared__ uint2 scf[32];
    if (threadIdx.x < 32) {
        uint2 v = {0, 0};
        if (threadIdx.x < 16) v = *(const uint2*)(coeffs + threadIdx.x * 4);
        scf[threadIdx.x] = v;   // scf[16] = {0,0} handles sentinel (rel=16)
    }
    __syncthreads();
    const int wave = threadIdx.x >> 6, lane = threadIdx.x & 63;
    const int n = blockIdx.x * 4 + wave;   // grid exact: N_ENTS/4
    int cn = cnt[n]; if (cn > BCAP) cn = BCAP;
    const int q = (cn + 7) >> 3;
    const uint4* __restrict__ bk = (const uint4*)(bucket + (size_t)n * BCAP);
    float lo[4][NB] = {}, hi[4][NB] = {};
    const uint* __restrict__ x32 = (const uint*)xrow;
    for (int i = 0; i < q; ++i) {
        const uint4 r0 = bk[i * 2];
        const uint4 r1 = bk[i * 2 + 1];
        const uint rec[8] = {r0.x, r0.y, r0.z, r0.w, r1.x, r1.y, r1.z, r1.w};
        uint xw[8];
#pragma unroll
        for (int s = 0; s < 8; ++s)
            xw[s] = x32[(size_t)(rec[s] & 0xFFFFFu) * 64 + lane];
#pragma unroll
        for (int s = 0; s < 8; ++s) {
            const uint2 cc = scf[rec[s] >> 20];
            const float cb[NB] = {bflo(cc.x), bfhi(cc.x), bflo(cc.y), bfhi(cc.y)};
            const float xl = bflo(xw[s]), xh = bfhi(xw[s]);
#pragma unroll
            for (int b = 0; b < NB; ++b) {
                lo[s & 3][b] = fmaf(cb[b], xl, lo[s & 3][b]);
                hi[s & 3][b] = fmaf(cb[b], xh, hi[s & 3][b]);
            }
        }
    }
    const size_t tb = (size_t)(n >> 4) * TILE_U + (n & 15) * 8;
#pragma unroll
    for (int b = 0; b < NB; ++b) {
        const float l = (lo[0][b] + lo[1][b]) + (lo[2][b] + lo[3][b]);
        const float h = (hi[0][b] + hi[1][b]) + (hi[2][b] + hi[3][b]);
        *(uint*)(xyT + tb + (size_t)(16 + b * 16 + (lane >> 2)) * 128 + (lane & 3) * 2) = pack2(l, h);
    }
}

// ---------------- build WtT tiled for BOTH layers: [l][jt 8][kc 80][r 16][8] ----------------
__global__ __launch_bounds__(256) void k_transw2(const unsigned short* __restrict__ par,
                                                 unsigned short* __restrict__ WtT) {
    const int i = blockIdx.x * 256 + threadIdx.x;   // grid exact: 20480/256 = 80
    const int l = i / 10240;
    const int rem = i - l * 10240;
    const int jt2 = rem / 1280;
    const int rem2 = rem - jt2 * 1280;
    const int kc = rem2 >> 4, r = rem2 & 15;
    const int n = jt2 * 16 + r;
    unsigned short v[8];
#pragma unroll
    for (int e = 0; e < 8; ++e) {
        const int k = kc * 8 + e;
        v[e] = (k < DIM)
            ? par[P_WSL + l * DIM * DIM + k * DIM + n]
            : par[P_BASES + l * NB * DIM * DIM + (k - DIM) * DIM + n];
    }
    *(uint4*)(WtT + (size_t)l * 81920 + (size_t)jt2 * TILE_U + (size_t)kc * 128 + r * 8) = *(uint4*)v;
}

// ---------------- tiled MFMA GEMM, depth-3 register pipeline + sched groups ----------------
#define LDSET(P, s) \
    P##a0 = *(const short8*)(pA0 + (s) * 512); \
    P##a1 = *(const short8*)(pA1 + (s) * 512); \
    P##a2 = *(const short8*)(pA2 + (s) * 512); \
    P##a3 = *(const short8*)(pA3 + (s) * 512); \
    P##b0 = *(const short8*)(pB0 + (s) * 512); \
    P##b1 = *(const short8*)(pB1 + (s) * 512); \
    P##b2 = *(const short8*)(pB2 + (s) * 512); \
    P##b3 = *(const short8*)(pB3 + (s) * 512);

#define MMSET(P) \
    acc[0][0] = __builtin_amdgcn_mfma_f32_16x16x32_bf16(P##a0, P##b0, acc[0][0], 0, 0, 0); \
    acc[0][1] = __builtin_amdgcn_mfma_f32_16x16x32_bf16(P##a0, P##b1, acc[0][1], 0, 0, 0); \
    acc[0][2] = __builtin_amdgcn_mfma_f32_16x16x32_bf16(P##a0, P##b2, acc[0][2], 0, 0, 0); \
    acc[0][3] = __builtin_amdgcn_mfma_f32_16x16x32_bf16(P##a0, P##b3, acc[0][3], 0, 0, 0); \
    acc[1][0] = __builtin_amdgcn_mfma_f32_16x16x32_bf16(P##a1, P##b0, acc[1][0], 0, 0, 0); \
    acc[1][1] = __builtin_amdgcn_mfma_f32_16x16x32_bf16(P##a1, P##b1, acc[1][1], 0, 0, 0); \
    acc[1][2] = __builtin_amdgcn_mfma_f32_16x16x32_bf16(P##a1, P##b2, acc[1][2], 0, 0, 0); \
    acc[1][3] = __builtin_amdgcn_mfma_f32_16x16x32_bf16(P##a1, P##b3, acc[1][3], 0, 0, 0); \
    acc[2][0] = __builtin_amdgcn_mfma_f32_16x16x32_bf16(P##a2, P##b0, acc[2][0], 0, 0, 0); \
    acc[2][1] = __builtin_amdgcn_mfma_f32_16x16x32_bf16(P##a2, P##b1, acc[2][1], 0, 0, 0); \
    acc[2][2] = __builtin_amdgcn_mfma_f32_16x16x32_bf16(P##a2, P##b2, acc[2][2], 0, 0, 0); \
    acc[2][3] = __builtin_amdgcn_mfma_f32_16x16x32_bf16(P##a2, P##b3, acc[2][3], 0, 0, 0); \
    acc[3][0] = __builtin_amdgcn_mfma_f32_16x16x32_bf16(P##a3, P##b0, acc[3][0], 0, 0, 0); \
    acc[3][1] = __builtin_amdgcn_mfma_f32_16x16x32_bf16(P##a3, P##b1, acc[3][1], 0, 0, 0); \
    acc[3][2] = __builtin_amdgcn_mfma_f32_16x16x32_bf16(P##a3, P##b2, acc[3][2], 0, 0, 0); \
    acc[3][3] = __builtin_amdgcn_mfma_f32_16x16x32_bf16(P##a3, P##b3, acc[3][3], 0, 0, 0);

// scheduling groups: 8 VMEM-reads (0x020), 16 MFMA (0x008)
#define SGB_LD __builtin_amdgcn_sched_group_barrier(0x020, 8, 0);
#define SGB_MM __builtin_amdgcn_sched_group_barrier(0x008, 16, 0);

__global__ __launch_bounds__(256) void k_gemm(
    const unsigned short* __restrict__ xyT, const unsigned short* __restrict__ wtT,
    const unsigned short* __restrict__ bsl, const int* __restrict__ cnt,
    unsigned short* __restrict__ out, float* __restrict__ pstats)
{
    const int tid = threadIdx.x;
    const int wave = tid >> 6, lane = tid & 63;
    const int quad = lane >> 4, l16 = lane & 15;
    const int m0 = blockIdx.x * 128;
    const int rbase = (wave >> 1) * 64;
    const int col0 = (wave & 1) * 64;

    const int gmt = blockIdx.x * 8 + (wave >> 1) * 4;
    const unsigned short* pA0 = xyT + (size_t)(gmt + 0) * TILE_U + quad * 128 + l16 * 8;
    const unsigned short* pA1 = xyT + (size_t)(gmt + 1) * TILE_U + quad * 128 + l16 * 8;
    const unsigned short* pA2 = xyT + (size_t)(gmt + 2) * TILE_U + quad * 128 + l16 * 8;
    const unsigned short* pA3 = xyT + (size_t)(gmt + 3) * TILE_U + quad * 128 + l16 * 8;
    const int jt0 = (wave & 1) * 4;
    const unsigned short* pB0 = wtT + (size_t)(jt0 + 0) * TILE_U + quad * 128 + l16 * 8;
    const unsigned short* pB1 = wtT + (size_t)(jt0 + 1) * TILE_U + quad * 128 + l16 * 8;
    const unsigned short* pB2 = wtT + (size_t)(jt0 + 2) * TILE_U + quad * 128 + l16 * 8;
    const unsigned short* pB3 = wtT + (size_t)(jt0 + 3) * TILE_U + quad * 128 + l16 * 8;

    f4 acc[4][4];
#pragma unroll
    for (int i = 0; i < 4; ++i)
#pragma unroll
        for (int j = 0; j < 4; ++j)
#pragma unroll
            for (int r = 0; r < 4; ++r) acc[i][j][r] = 0.f;

    short8 xa0, xa1, xa2, xa3, xb0, xb1, xb2, xb3;
    short8 ya0, ya1, ya2, ya3, yb0, yb1, yb2, yb3;
    short8 za0, za1, za2, za3, zb0, zb1, zb2, zb3;

    LDSET(x, 0)  SGB_LD
    LDSET(y, 1)  SGB_LD
    LDSET(z, 2)  SGB_LD
    MMSET(x) SGB_MM LDSET(x, 3)  SGB_LD
    MMSET(y) SGB_MM LDSET(y, 4)  SGB_LD
    MMSET(z) SGB_MM LDSET(z, 5)  SGB_LD
    MMSET(x) SGB_MM LDSET(x, 6)  SGB_LD
    MMSET(y) SGB_MM LDSET(y, 7)  SGB_LD
    MMSET(z) SGB_MM LDSET(z, 8)  SGB_LD
    MMSET(x) SGB_MM LDSET(x, 9)  SGB_LD
    MMSET(y) SGB_MM LDSET(y, 10) SGB_LD
    MMSET(z) SGB_MM LDSET(z, 11) SGB_LD
    MMSET(x) SGB_MM LDSET(x, 12) SGB_LD
    MMSET(y) SGB_MM LDSET(y, 13) SGB_LD
    MMSET(z) SGB_MM LDSET(z, 14) SGB_LD
    MMSET(x) SGB_MM LDSET(x, 15) SGB_LD
    MMSET(y) SGB_MM LDSET(y, 16) SGB_LD
    MMSET(z) SGB_MM LDSET(z, 17) SGB_LD
    MMSET(x) SGB_MM LDSET(x, 18) SGB_LD
    MMSET(y) SGB_MM LDSET(y, 19) SGB_LD
    MMSET(z) SGB_MM
    MMSET(x) SGB_MM
    MMSET(y) SGB_MM

    // epilogue: o = (acc + bias)/deg ; store bf16 ; block-local BN stats
    float s_sum[4] = {0, 0, 0, 0}, s_ssq[4] = {0, 0, 0, 0};
#pragma unroll
    for (int i = 0; i < 4; ++i) {
#pragma unroll
        for (int r = 0; r < 4; ++r) {
            const int row = m0 + rbase + i * 16 + quad * 4 + r;
            const int rc = row < N_ENTS ? row : N_ENTS - 1;
            const float rdeg = 1.0f / fmaxf((float)cnt[rc], 1.0f);
            const bool valid = row < N_ENTS;
#pragma unroll
            for (int j = 0; j < 4; ++j) {
                const int f = col0 + j * 16 + l16;
                const float o = (acc[i][j][r] + bf2f(bsl[f])) * rdeg;
                if (valid) {
                    out[(size_t)row * DIM + f] = f2bf(o);
                    s_sum[j] += o;
                    s_ssq[j] += o * o;
                }
            }
        }
    }
    __shared__ float ssum[4][64], sssq[4][64];
#pragma unroll
    for (int j = 0; j < 4; ++j) {
        float s = s_sum[j], q2 = s_ssq[j];
        s += __shfl_xor(s, 16, 64); s += __shfl_xor(s, 32, 64);
        q2 += __shfl_xor(q2, 16, 64); q2 += __shfl_xor(q2, 32, 64);
        if (quad == 0) {
            ssum[wave][j * 16 + l16] = s;
            sssq[wave][j * 16 + l16] = q2;
        }
    }
    __syncthreads();
    {
        const int f = tid & 127;
        const int g = f >> 6;
        const int fl = f & 63;
        const float v = (tid < 128) ? (ssum[g][fl] + ssum[g + 2][fl])
                                    : (sssq[g][fl] + sssq[g + 2][fl]);
        pstats[(size_t)blockIdx.x * 256 + tid] = v;
    }
}

// ---------------- reduce per-block stats -> st[256] ----------------
__global__ __launch_bounds__(256) void k_stats(const float* __restrict__ pstats,
                                               float* __restrict__ st) {
    const int o = threadIdx.x;
    const int b0 = blockIdx.x * 49;
    float s = 0.f;
    for (int b = b0; b < b0 + 49 && b < NBLK; ++b)
        s += pstats[(size_t)b * 256 + o];
    atomicAdd(&st[o], s);
}

// ---------------- BN apply + ReLU: outb(bf16) -> xrow (+ xyT x-cols if l==0) ----------------
__global__ __launch_bounds__(256) void k_bn(
    const unsigned short* __restrict__ out, const float* __restrict__ st,
    const unsigned short* __restrict__ gamma, const unsigned short* __restrict__ beta,
    unsigned short* __restrict__ xrow, unsigned short* __restrict__ xyT, int writeTiled)
{
    const int tile = blockIdx.x;                 // grid exact: 6250
    const int kc = threadIdx.x >> 4, r = threadIdx.x & 15;
    const int n = tile * 16 + r;
    const size_t e0 = (size_t)n * DIM + kc * 8;
    const uint4 u = *(const uint4*)(out + e0);
    const uint uu[4] = {u.x, u.y, u.z, u.w};
    const float inv_n = 1.0f / (float)N_ENTS;
    uint w[4];
#pragma unroll
    for (int p = 0; p < 4; ++p) {
        const int f0 = kc * 8 + p * 2;
        float v0 = bflo(uu[p]), v1 = bfhi(uu[p]);
        const float mu0 = st[f0] * inv_n, mu1 = st[f0 + 1] * inv_n;
        const float var0 = st[DIM + f0] * inv_n - mu0 * mu0;
        const float var1 = st[DIM + f0 + 1] * inv_n - mu1 * mu1;
        const float g0 = bf2f(gamma[f0]) * rsqrtf(var0 + BN_EPS);
        const float g1 = bf2f(gamma[f0 + 1]) * rsqrtf(var1 + BN_EPS);
        v0 = fmaxf((v0 - mu0) * g0 + bf2f(beta[f0]), 0.f);
        v1 = fmaxf((v1 - mu1) * g1 + bf2f(beta[f0 + 1]), 0.f);
        w[p] = pack2(v0, v1);
    }
    uint4 wv = {w[0], w[1], w[2], w[3]};
    *(uint4*)(xrow + e0) = wv;
    if (writeTiled)
        *(uint4*)(xyT + (size_t)tile * TILE_U + kc * 128 + r * 8) = wv;
}

// ---------------- fused scoring (hr recomputed inline) ----------------
__global__ __launch_bounds__(256) void k_score(
    const int* __restrict__ head, const int* __restrict__ rel,
    const int* __restrict__ tail, const int* __restrict__ negi,
    const unsigned short* __restrict__ xrow, const unsigned short* __restrict__ rtab,
    void* __restrict__ outp, const int* __restrict__ flag)
{
    const int wave = threadIdx.x >> 6, lane = threadIdx.x & 63;
    const int w = blockIdx.x * 4 + wave;   // grid exact: (BATCH + BATCH*NNEG)/4
    int i, t;
    if (w < BATCH) { i = w; t = tail[w]; }
    else { const int w2 = w - BATCH; i = w2 >> 6; t = negi[w2]; }
    const uint hv = ((const uint*)xrow)[(size_t)head[i] * 64 + lane];
    const uint rv = ((const uint*)rtab)[(size_t)rel[i] * 64 + lane];
    const uint tv = ((const uint*)xrow)[(size_t)t * 64 + lane];
    const float d0 = (bflo(hv) + bflo(rv)) - bflo(tv);
    const float d1 = (bfhi(hv) + bfhi(rv)) - bfhi(tv);
    float s = d0 * d0 + d1 * d1;
#pragma unroll
    for (int m = 32; m >= 1; m >>= 1) s += __shfl_xor(s, m, 64);
    if (lane == 0) {
        const float v = -sqrtf(s);
        if (flag[0]) ((unsigned short*)outp)[w] = f2bf(v);
        else         ((float*)outp)[w] = v;
    }
}

extern "C" void kernel_launch(void* const* d_in, const int* in_sizes, int n_in,
                              void* d_out, int out_size, void* d_ws, size_t ws_size,
                              hipStream_t stream)
{
    const int* head = (const int*)d_in[0];
    const int* rel  = (const int*)d_in[1];
    const int* tail = (const int*)d_in[2];
    const int* negi = (const int*)d_in[3];
    const int* eidx = (const int*)d_in[4];
    const int* etyp = (const int*)d_in[5];
    const void* ent_tab = d_in[6];
    const void* rtab_in = d_in[7];
    const void* bases_in = d_in[8];
    const void* coeffs_in = d_in[9];
    const void* wsl_in = d_in[10];
    const void* bsl_in = d_in[11];
    const void* gamma_in = d_in[12];
    const void* beta_in = d_in[13];

    char* ws = (char*)d_ws;
    size_t off = 0;
    auto alloc = [&](size_t bytes) -> char* {
        char* p = ws + off;
        off += (bytes + 511) & ~(size_t)511;
        return p;
    };
    int* flag            = (int*)alloc(4);
    int* cnt             = (int*)alloc((size_t)N_ENTS * 4);
    uint* bucket         = (uint*)alloc((size_t)N_ENTS * BCAP * 4);             // 25.6 MB
    unsigned short* xyT  = (unsigned short*)alloc((size_t)NTILES * TILE_U * 2); // 128.1 MB tiled
    unsigned short* xrow = (unsigned short*)alloc((size_t)N_ENTS * DIM * 2);    // 25.6 MB row-major
    unsigned short* outb = (unsigned short*)alloc((size_t)M_PAD * DIM * 2);     // 25.6 MB bf16
    unsigned short* par  = (unsigned short*)alloc((size_t)P_TOTAL * 2);
    unsigned short* WtT  = (unsigned short*)alloc((size_t)2 * 81920 * 2);
    float* pstats        = (float*)alloc((size_t)NBLK * 256 * 4);
    float* stats         = (float*)alloc(2 * 2 * DIM * 4);
    (void)ws_size; (void)in_sizes; (void)n_in; (void)out_size;

    const int* esrc = eidx;
    const int* edst = eidx + NEDGE;

    k_detect<<<1, 256, 0, stream>>>((const unsigned int*)ent_tab, flag);

    k_conv_x<<<N_ENTS / 16, 256, 0, stream>>>(ent_tab, xrow, xyT, flag);
    k_conv_params<<<(P_TOTAL + 255) / 256, 256, 0, stream>>>(
        rtab_in, bases_in, coeffs_in, wsl_in, bsl_in, gamma_in, beta_in, par, flag);
    k_transw2<<<80, 256, 0, stream>>>(par, WtT);

    hipMemsetAsync(cnt, 0, (size_t)N_ENTS * 4, stream);
    hipMemsetAsync(stats, 0, 2 * 2 * DIM * 4, stream);

    k_fillB<<<NEDGE / 256, 256, 0, stream>>>(esrc, edst, etyp, cnt, bucket);
    k_pad<<<(N_ENTS + 255) / 256, 256, 0, stream>>>(cnt, bucket);

    for (int l = 0; l < 2; ++l) {
        const unsigned short* bl = par + P_BSL   + l * DIM;
        const unsigned short* cf = par + P_COEFF + l * N_RELS * NB;
        const unsigned short* gm = par + P_GAMMA + l * DIM;
        const unsigned short* bt = par + P_BETA  + l * DIM;
        const unsigned short* wt = WtT + (size_t)l * 81920;
        float* st = stats + l * 2 * DIM;

        k_agg<<<N_ENTS / 4, 256, 0, stream>>>(bucket, cnt, cf, xrow, xyT);
        k_gemm<<<NBLK, 256, 0, stream>>>(xyT, wt, bl, cnt, outb, pstats);
        k_stats<<<16, 256, 0, stream>>>(pstats, st);
        k_bn<<<N_ENTS / 16, 256, 0, stream>>>(outb, st, gm, bt, xrow, xyT, l == 0 ? 1 : 0);
    }

    k_score<<<(BATCH + BATCH * NNEG) / 4, 256, 0, stream>>>(
        head, rel, tail, negi, xrow, par + P_REL, d_out, flag);
}